// Round 1
// baseline (2081.157 us; speedup 1.0000x reference)
//
#include <hip/hip_runtime.h>

// FlatST: GAT autoencoder + smoothing, f32.
// N=100000, E=800000, IN=256, HID=128, OUT=32.
//
// Restructured: aggregate-then-GEMM (linearity of segment_sum), xd GEMMs
// folded into per-node dot products with precomputed W@a vectors, softmax
// denominator divided out per-node, two static smoothing chains fused into
// one (scalar multiples of the same matrix).

#define SELU_S 1.0507009873554805f
#define SELU_A 1.6732632423543772f

__device__ __forceinline__ float selu_f(float v){
  return v > 0.f ? SELU_S * v : SELU_S * SELU_A * (__expf(v) - 1.f);
}
// monotone float<->uint key for atomicMax on floats
__device__ __forceinline__ unsigned fkey(float f){
  unsigned u = __float_as_uint(f);
  return (u & 0x80000000u) ? ~u : (u | 0x80000000u);
}
__device__ __forceinline__ float funkey(unsigned k){
  unsigned u = (k & 0x80000000u) ? (k & 0x7fffffffu) : ~k;
  return __uint_as_float(u);
}

// ---------- small precompute: u = W@a vectors + smoothing scalar ----------
__global__ void precompute_vecs(const float* __restrict__ W1s, const float* __restrict__ W1d,
                                const float* __restrict__ a1s, const float* __restrict__ a1d,
                                const float* __restrict__ W2s, const float* __restrict__ W2d,
                                const float* __restrict__ a2s, const float* __restrict__ a2d,
                                const float* __restrict__ a3s, const float* __restrict__ a3d,
                                float* u1, float* v1, float* u2, float* v2,
                                float* u3, float* v3,
                                const float* alpha1, const float* alpha2, float* sscale){
  int t = threadIdx.x; // 256 threads
  float s1 = 0.f, s2 = 0.f;
  for (int j = 0; j < 128; j++){ s1 += W1s[t*128+j]*a1s[j]; s2 += W1d[t*128+j]*a1d[j]; }
  u1[t] = s1; v1[t] = s2;
  if (t < 128){
    float s3 = 0.f, s4 = 0.f;
    for (int j = 0; j < 32; j++){ s3 += W2s[t*32+j]*a2s[j]; s4 += W2d[t*32+j]*a2d[j]; }
    u2[t] = s3; v2[t] = s4;
  }
  if (t < 32){
    float s5 = 0.f, s6 = 0.f;
    for (int j = 0; j < 128; j++){ s5 += W2s[j*32+t]*a3s[j]; s6 += W2d[j*32+t]*a3d[j]; }
    u3[t] = s5; v3[t] = s6;
  }
  if (t == 0){
    float a = alpha1[0], b = alpha2[0];
    sscale[0] = 0.5f * (a*a + 4.f*b*b);
  }
}

// ---------- per-node dot pair: p[n]=X[n]@u, q[n]=X[n]@v (one wave/node) ----------
template<int DIM>
__global__ void node_dots(const float* __restrict__ X, const float* __restrict__ u,
                          const float* __restrict__ v, float* __restrict__ p,
                          float* __restrict__ q, int N){
  int g = blockIdx.x * blockDim.x + threadIdx.x;
  int wave = g >> 6, lane = g & 63;
  if (wave >= N) return;
  float s1 = 0.f, s2 = 0.f;
  for (int k = lane; k < DIM; k += 64){
    float x = X[(size_t)wave*DIM + k];
    s1 += x * u[k]; s2 += x * v[k];
  }
  for (int off = 32; off; off >>= 1){ s1 += __shfl_down(s1, off); s2 += __shfl_down(s2, off); }
  if (lane == 0){ p[wave] = s1; q[wave] = s2; }
}

// ---------- degree counts ----------
__global__ void deg_kernel(const int* __restrict__ src, const int* __restrict__ dst,
                           float* deg_src, float* deg_in, int E){
  int e = blockIdx.x * blockDim.x + threadIdx.x;
  if (e >= E) return;
  atomicAdd(&deg_src[src[e]], 1.f);
  atomicAdd(&deg_in[dst[e]], 1.f);
}

// ---------- attention: score + segment max ----------
__global__ void edge_score_max(const int* __restrict__ src, const int* __restrict__ dst,
                               const float* __restrict__ ps, const float* __restrict__ pd,
                               float* __restrict__ sarr, unsigned* __restrict__ mxkey, int E){
  int e = blockIdx.x * blockDim.x + threadIdx.x;
  if (e >= E) return;
  float s = ps[src[e]] + pd[dst[e]];
  s = s > 0.f ? s : 0.2f * s;   // leaky_relu 0.2
  sarr[e] = s;
  atomicMax(&mxkey[dst[e]], fkey(s));
}

// ---------- attention: exp + segment denominator ----------
__global__ void edge_exp_den(const int* __restrict__ dst, float* __restrict__ sarr,
                             const unsigned* __restrict__ mxkey, float* __restrict__ den, int E){
  int e = blockIdx.x * blockDim.x + threadIdx.x;
  if (e >= E) return;
  int d = dst[e];
  float ee = __expf(sarr[e] - funkey(mxkey[d]));
  sarr[e] = ee;
  atomicAdd(&den[d], ee);
}

// ---------- edge aggregation: out[sidx] += w * xin[gidx] ----------
// WMODE 0: w = earr[e]   (attention, unnormalized)
// WMODE 1: w = 1         (uniform)
// WMODE 2: w = p[sidx]*q[gidx] (* sscale if non-null)  (smoothing)
template<int DIM, int WMODE>
__global__ void edge_aggregate(const int* __restrict__ gidx, const int* __restrict__ sidx,
                               const float* __restrict__ earr,
                               const float* __restrict__ p, const float* __restrict__ q,
                               const float* __restrict__ sscale,
                               const float* __restrict__ xin, float* __restrict__ out, int E){
  size_t g = (size_t)blockIdx.x * blockDim.x + threadIdx.x;
  if (g >= (size_t)E * DIM) return;
  int e = (int)(g / DIM);
  int k = (int)(g % DIM);
  int gi = gidx[e], si = sidx[e];
  float w;
  if (WMODE == 0) w = earr[e];
  else if (WMODE == 1) w = 1.f;
  else { w = p[si] * q[gi]; if (sscale) w *= sscale[0]; }
  atomicAdd(&out[(size_t)si * DIM + k], w * xin[(size_t)gi * DIM + k]);
}

// ---------- per-node normalize (+ optional selu), in place ----------
template<int DIM, bool DO_SELU>
__global__ void node_finalize(float* __restrict__ buf, const float* __restrict__ den, int N){
  int g = blockIdx.x * blockDim.x + threadIdx.x;
  if (g >= N * DIM) return;
  int n = g / DIM;
  float d = den[n];
  float v = 0.f;
  if (d > 0.f){
    v = buf[g] / d;
    if (DO_SELU) v = selu_f(v);
  }
  buf[g] = v;
}

// ---------- smoothing per-node coefficients ----------
__global__ void smooth_node(const float* __restrict__ deg, float* dis, float* pna, float* qn, int N){
  int n = blockIdx.x * blockDim.x + threadIdx.x;
  if (n >= N) return;
  float d = deg[n];
  float di = d > 0.f ? powf(d, -0.6f) : 0.f;
  float d2 = d > 0.f ? powf(d, -0.5f) : 0.f;
  float al = 1.f / (1.f + logf(d + 1.f));
  dis[n] = di; pna[n] = d2 * al; qn[n] = d2;
}

// ---------- tiled f32 GEMM: C[M,K] = A[M,D] @ B  (optional selu epilogue) ----------
// TRANSB=false: B stored [D,K] row-major. TRANSB=true: B stored [K,D] row-major (C = A @ Bstored^T).
template<bool TRANSB, bool DO_SELU>
__global__ __launch_bounds__(256) void gemm_kernel(const float* __restrict__ A, const float* __restrict__ B,
                            float* __restrict__ C, int M, int D, int K){
  __shared__ float As[16][68];
  __shared__ float Bs[16][68];
  int tid = threadIdx.x;
  int tx = tid & 15, ty = tid >> 4;
  int row0 = blockIdx.x * 64;
  int col0 = blockIdx.y * 64;
  float acc[4][4] = {};
  for (int d0 = 0; d0 < D; d0 += 16){
    #pragma unroll
    for (int i = 0; i < 4; i++){
      int l = tid + i * 256;
      int m = l >> 4, d = l & 15;
      int r = row0 + m;
      As[d][m] = (r < M) ? A[(size_t)r * D + d0 + d] : 0.f;
    }
    #pragma unroll
    for (int i = 0; i < 4; i++){
      int l = tid + i * 256;
      int d, k;
      if (TRANSB){ d = l & 15; k = l >> 4; }
      else       { k = l & 63; d = l >> 6; }
      int kk = col0 + k;
      float v = 0.f;
      if (kk < K) v = TRANSB ? B[(size_t)kk * D + d0 + d] : B[(size_t)(d0 + d) * K + kk];
      Bs[d][k] = v;
    }
    __syncthreads();
    #pragma unroll
    for (int d = 0; d < 16; d++){
      float a[4], b[4];
      #pragma unroll
      for (int i = 0; i < 4; i++) a[i] = As[d][ty*4 + i];
      #pragma unroll
      for (int j = 0; j < 4; j++) b[j] = Bs[d][tx*4 + j];
      #pragma unroll
      for (int i = 0; i < 4; i++)
        #pragma unroll
        for (int j = 0; j < 4; j++)
          acc[i][j] += a[i] * b[j];
    }
    __syncthreads();
  }
  #pragma unroll
  for (int i = 0; i < 4; i++){
    int r = row0 + ty*4 + i;
    if (r >= M) continue;
    #pragma unroll
    for (int j = 0; j < 4; j++){
      int c = col0 + tx*4 + j;
      if (c >= K) continue;
      float v = acc[i][j];
      if (DO_SELU) v = selu_f(v);
      C[(size_t)r * K + c] = v;
    }
  }
}

extern "C" void kernel_launch(void* const* d_in, const int* in_sizes, int n_in,
                              void* d_out, int out_size, void* d_ws, size_t ws_size,
                              hipStream_t stream){
  const float* X    = (const float*)d_in[0];
  const int*   eidx = (const int*)d_in[1];
  const float* W1s  = (const float*)d_in[2];
  const float* W1d  = (const float*)d_in[3];
  const float* a1s  = (const float*)d_in[4];
  const float* a1d  = (const float*)d_in[5];
  const float* W2s  = (const float*)d_in[6];
  const float* W2d  = (const float*)d_in[7];
  const float* a2s  = (const float*)d_in[8];
  const float* a2d  = (const float*)d_in[9];
  const float* a3s  = (const float*)d_in[10];
  const float* a3d  = (const float*)d_in[11];
  const float* alpha1 = (const float*)d_in[14];
  const float* alpha2 = (const float*)d_in[15];

  const int N = in_sizes[0] / 256;
  const int E = in_sizes[1] / 2;
  const int* src = eidx;
  const int* dst = eidx + E;

  float* out_sm = (float*)d_out;                    // [N,32]
  float* out_h4 = (float*)d_out + (size_t)N * 32;   // [N,256]

  float* ws = (float*)d_ws;
  size_t o = 0;
  float* B1 = ws + o; o += (size_t)N * 128;  // xs1, later h3
  float* B2 = ws + o; o += (size_t)N * 128;  // agg1->h1, later agg(h3)
  float* B3 = ws + o; o += (size_t)N * 32;   // xs2, later smooth tmp
  float* B4 = ws + o; o += (size_t)N * 32;   // agg2->h2 (smoothing seed)
  float* B5 = ws + o; o += (size_t)N * 32;   // agg3, later smooth tmp
  float* ps = ws + o; o += N;
  float* pd = ws + o; o += N;
  float* sarr = ws + o; o += E;
  float* den  = ws + o; o += N;
  unsigned* mxkey = (unsigned*)(ws + o); o += N;
  float* deg_in  = ws + o; o += N;
  float* deg_src = ws + o; o += N;
  float* dis = ws + o; o += N;
  float* pna = ws + o; o += N;
  float* qn  = ws + o; o += N;
  float* u1 = ws + o; o += 256;
  float* v1 = ws + o; o += 256;
  float* u2 = ws + o; o += 128;
  float* v2 = ws + o; o += 128;
  float* u3 = ws + o; o += 32;
  float* v3 = ws + o; o += 32;
  float* sscale = ws + o; o += 1;

  const int TPB = 256;
  const int EB = (E + TPB - 1) / TPB;
  auto blocksFor = [](size_t n){ return (unsigned)((n + 255) / 256); };

  // ---- init ----
  hipMemsetAsync(mxkey, 0, (size_t)N * 4, stream);
  hipMemsetAsync(den, 0, (size_t)N * 4, stream);
  hipMemsetAsync(B2, 0, (size_t)N * 128 * 4, stream);
  hipMemsetAsync(deg_in, 0, (size_t)N * 4, stream);
  hipMemsetAsync(deg_src, 0, (size_t)N * 4, stream);
  hipMemsetAsync(out_sm, 0, (size_t)N * 32 * 4, stream);

  precompute_vecs<<<1, 256, 0, stream>>>(W1s, W1d, a1s, a1d, W2s, W2d, a2s, a2d,
                                         a3s, a3d, u1, v1, u2, v2, u3, v3,
                                         alpha1, alpha2, sscale);
  deg_kernel<<<EB, TPB, 0, stream>>>(src, dst, deg_src, deg_in, E);

  // ---- GAT layer 1: X(256) -> h1(128) ----
  node_dots<256><<<blocksFor((size_t)N * 64), TPB, 0, stream>>>(X, u1, v1, ps, pd, N);
  {
    dim3 g((N + 63) / 64, 2);
    gemm_kernel<false, false><<<g, TPB, 0, stream>>>(X, W1s, B1, N, 256, 128); // xs1
  }
  edge_score_max<<<EB, TPB, 0, stream>>>(src, dst, ps, pd, sarr, mxkey, E);
  edge_exp_den<<<EB, TPB, 0, stream>>>(dst, sarr, mxkey, den, E);
  edge_aggregate<128, 0><<<blocksFor((size_t)E * 128), TPB, 0, stream>>>(
      src, dst, sarr, nullptr, nullptr, nullptr, B1, B2, E);
  node_finalize<128, true><<<blocksFor((size_t)N * 128), TPB, 0, stream>>>(B2, den, N); // h1

  // ---- GAT layer 2: h1(128) -> h2(32) ----
  node_dots<128><<<blocksFor((size_t)N * 64), TPB, 0, stream>>>(B2, u2, v2, ps, pd, N);
  {
    dim3 g((N + 63) / 64, 1);
    gemm_kernel<false, false><<<g, TPB, 0, stream>>>(B2, W2s, B3, N, 128, 32); // xs2
  }
  hipMemsetAsync(mxkey, 0, (size_t)N * 4, stream);
  hipMemsetAsync(den, 0, (size_t)N * 4, stream);
  hipMemsetAsync(B4, 0, (size_t)N * 32 * 4, stream);
  edge_score_max<<<EB, TPB, 0, stream>>>(src, dst, ps, pd, sarr, mxkey, E);
  edge_exp_den<<<EB, TPB, 0, stream>>>(dst, sarr, mxkey, den, E);
  edge_aggregate<32, 0><<<blocksFor((size_t)E * 32), TPB, 0, stream>>>(
      src, dst, sarr, nullptr, nullptr, nullptr, B3, B4, E);
  node_finalize<32, false><<<blocksFor((size_t)N * 32), TPB, 0, stream>>>(B4, den, N); // h2

  // ---- GAT layer 3: h2(32) -> h3(128), aggregate h2 then GEMM with W2s^T ----
  node_dots<32><<<blocksFor((size_t)N * 64), TPB, 0, stream>>>(B4, u3, v3, ps, pd, N);
  hipMemsetAsync(mxkey, 0, (size_t)N * 4, stream);
  hipMemsetAsync(den, 0, (size_t)N * 4, stream);
  hipMemsetAsync(B5, 0, (size_t)N * 32 * 4, stream);
  edge_score_max<<<EB, TPB, 0, stream>>>(src, dst, ps, pd, sarr, mxkey, E);
  edge_exp_den<<<EB, TPB, 0, stream>>>(dst, sarr, mxkey, den, E);
  edge_aggregate<32, 0><<<blocksFor((size_t)E * 32), TPB, 0, stream>>>(
      src, dst, sarr, nullptr, nullptr, nullptr, B4, B5, E);
  node_finalize<32, false><<<blocksFor((size_t)N * 32), TPB, 0, stream>>>(B5, den, N);
  {
    dim3 g((N + 63) / 64, 2);
    gemm_kernel<true, true><<<g, TPB, 0, stream>>>(B5, W2s, B1, N, 32, 128); // h3 = selu(. @ W2s^T)
  }

  // ---- GAT layer 4 (uniform attention): aggregate h3 then GEMM with W1s^T ----
  hipMemsetAsync(B2, 0, (size_t)N * 128 * 4, stream);
  edge_aggregate<128, 1><<<blocksFor((size_t)E * 128), TPB, 0, stream>>>(
      src, dst, nullptr, nullptr, nullptr, nullptr, B1, B2, E);
  node_finalize<128, false><<<blocksFor((size_t)N * 128), TPB, 0, stream>>>(B2, deg_in, N);
  {
    dim3 g((N + 63) / 64, 4);
    gemm_kernel<true, false><<<g, TPB, 0, stream>>>(B2, W1s, out_h4, N, 128, 256); // h4
  }

  // ---- smoothing: sm = Norm^2 * (0.5(a1^2+4a2^2) * C^2 h2) ----
  smooth_node<<<(N + TPB - 1) / TPB, TPB, 0, stream>>>(deg_src, dis, pna, qn, N);
  hipMemsetAsync(B3, 0, (size_t)N * 32 * 4, stream);
  edge_aggregate<32, 2><<<blocksFor((size_t)E * 32), TPB, 0, stream>>>(
      dst, src, nullptr, dis, dis, nullptr, B4, B3, E);
  hipMemsetAsync(B5, 0, (size_t)N * 32 * 4, stream);
  edge_aggregate<32, 2><<<blocksFor((size_t)E * 32), TPB, 0, stream>>>(
      dst, src, nullptr, dis, dis, sscale, B3, B5, E);
  hipMemsetAsync(B3, 0, (size_t)N * 32 * 4, stream);
  edge_aggregate<32, 2><<<blocksFor((size_t)E * 32), TPB, 0, stream>>>(
      dst, src, nullptr, pna, qn, nullptr, B5, B3, E);
  edge_aggregate<32, 2><<<blocksFor((size_t)E * 32), TPB, 0, stream>>>(
      dst, src, nullptr, pna, qn, nullptr, B3, out_sm, E);
}

// Round 2
// 973.850 us; speedup vs baseline: 2.1370x; 2.1370x over previous
//
#include <hip/hip_runtime.h>

// FlatST: GAT autoencoder + smoothing, f32, CSR-based (no atomics in hot path).
// N=100000, E=800000, IN=256, HID=128, OUT=32.

#define SELU_S 1.0507009873554805f
#define SELU_A 1.6732632423543772f

__device__ __forceinline__ float selu_f(float v){
  return v > 0.f ? SELU_S * v : SELU_S * SELU_A * (__expf(v) - 1.f);
}

// ---------- small precompute: u = W@a vectors + smoothing scalar ----------
__global__ void precompute_vecs(const float* __restrict__ W1s, const float* __restrict__ W1d,
                                const float* __restrict__ a1s, const float* __restrict__ a1d,
                                const float* __restrict__ W2s, const float* __restrict__ W2d,
                                const float* __restrict__ a2s, const float* __restrict__ a2d,
                                const float* __restrict__ a3s, const float* __restrict__ a3d,
                                float* u1, float* v1, float* u2, float* v2,
                                float* u3, float* v3,
                                const float* alpha1, const float* alpha2, float* sscale){
  int t = threadIdx.x; // 256 threads
  float s1 = 0.f, s2 = 0.f;
  for (int j = 0; j < 128; j++){ s1 += W1s[t*128+j]*a1s[j]; s2 += W1d[t*128+j]*a1d[j]; }
  u1[t] = s1; v1[t] = s2;
  if (t < 128){
    float s3 = 0.f, s4 = 0.f;
    for (int j = 0; j < 32; j++){ s3 += W2s[t*32+j]*a2s[j]; s4 += W2d[t*32+j]*a2d[j]; }
    u2[t] = s3; v2[t] = s4;
  }
  if (t < 32){
    float s5 = 0.f, s6 = 0.f;
    for (int j = 0; j < 128; j++){ s5 += W2s[j*32+t]*a3s[j]; s6 += W2d[j*32+t]*a3d[j]; }
    u3[t] = s5; v3[t] = s6;
  }
  if (t == 0){
    float a = alpha1[0], b = alpha2[0];
    sscale[0] = 0.5f * (a*a + 4.f*b*b);
  }
}

// ---------- per-node dot pair: p[n]=X[n]@u, q[n]=X[n]@v (one wave/node) ----------
template<int DIM>
__global__ void node_dots(const float* __restrict__ X, const float* __restrict__ u,
                          const float* __restrict__ v, float* __restrict__ p,
                          float* __restrict__ q, int N){
  int g = blockIdx.x * blockDim.x + threadIdx.x;
  int wave = g >> 6, lane = g & 63;
  if (wave >= N) return;
  float s1 = 0.f, s2 = 0.f;
  for (int k = lane; k < DIM; k += 64){
    float x = X[(size_t)wave*DIM + k];
    s1 += x * u[k]; s2 += x * v[k];
  }
  for (int off = 32; off; off >>= 1){ s1 += __shfl_down(s1, off); s2 += __shfl_down(s2, off); }
  if (lane == 0){ p[wave] = s1; q[wave] = s2; }
}

// ---------- degree histograms (int) ----------
__global__ void deg_int(const int* __restrict__ src, const int* __restrict__ dst,
                        int* dsrc, int* ddst, int E){
  int e = blockIdx.x * blockDim.x + threadIdx.x;
  if (e >= E) return;
  atomicAdd(&dsrc[src[e]], 1);
  atomicAdd(&ddst[dst[e]], 1);
}

// ---------- hierarchical exclusive scan (1024 elems / block) ----------
__global__ void scan_block(const int* __restrict__ in, int* __restrict__ out,
                           int* __restrict__ bsums, int n){
  __shared__ int tmp[256];
  int tid = threadIdx.x;
  int base = blockIdx.x * 1024 + tid * 4;
  int v[4];
  #pragma unroll
  for (int i = 0; i < 4; i++) v[i] = (base + i < n) ? in[base + i] : 0;
  int ts = v[0] + v[1] + v[2] + v[3];
  tmp[tid] = ts; __syncthreads();
  for (int off = 1; off < 256; off <<= 1){
    int t = (tid >= off) ? tmp[tid - off] : 0;
    __syncthreads();
    tmp[tid] += t;
    __syncthreads();
  }
  int excl = tmp[tid] - ts;
  if (tid == 255 && bsums) bsums[blockIdx.x] = tmp[255];
  int run = excl;
  #pragma unroll
  for (int i = 0; i < 4; i++){ if (base + i < n) out[base + i] = run; run += v[i]; }
}
__global__ void scan_add(int* __restrict__ out, const int* __restrict__ bscan, int n){
  int base = blockIdx.x * 1024 + threadIdx.x * 4;
  int b = bscan[blockIdx.x];
  #pragma unroll
  for (int i = 0; i < 4; i++){ if (base + i < n) out[base + i] += b; }
}

// ---------- CSR scatter: adj[pos] = other endpoint ----------
__global__ void scatter_csr(const int* __restrict__ key, const int* __restrict__ other,
                            int* __restrict__ cursor, int* __restrict__ adj, int E){
  int e = blockIdx.x * blockDim.x + threadIdx.x;
  if (e >= E) return;
  int pos = atomicAdd(&cursor[key[e]], 1);
  adj[pos] = other[e];
}

// ---------- fused GAT layer: softmax attention + aggregate + norm + selu ----------
// One G-lane group per node. ATTN: w = softmax(leaky(ps[adj]+pd[node])); else w = 1/deg.
template<int DIM, int G, bool ATTN, bool DO_SELU>
__global__ __launch_bounds__(256) void fused_gat(
    const int* __restrict__ off, const int* __restrict__ degs, const int* __restrict__ adj,
    const float* __restrict__ ps, const float* __restrict__ pd,
    const float* __restrict__ xin, float* __restrict__ out, int N){
  int t = blockIdx.x * 256 + threadIdx.x;
  int node = t / G;
  int gl = t % G;
  if (node >= N) return;
  int base = (threadIdx.x & 63) & ~(G - 1);
  int o = off[node], dg = degs[node];
  constexpr int R = DIM / G;
  float acc[R] = {};
  if (ATTN){
    float pdn = pd[node];
    float m = -1e30f;
    for (int k = gl; k < dg; k += G){
      float s = ps[adj[o + k]] + pdn;
      s = s > 0.f ? s : 0.2f * s;
      m = fmaxf(m, s);
    }
    for (int msk = G >> 1; msk; msk >>= 1) m = fmaxf(m, __shfl_xor(m, msk));
    float den = 0.f;
    for (int k = gl; k < dg; k += G){
      float s = ps[adj[o + k]] + pdn;
      s = s > 0.f ? s : 0.2f * s;
      den += __expf(s - m);
    }
    for (int msk = G >> 1; msk; msk >>= 1) den += __shfl_xor(den, msk);
    float inv = (dg > 0) ? 1.f / den : 0.f;
    for (int c0 = 0; c0 < dg; c0 += G){
      int cn = min(G, dg - c0);
      int nid = 0; float w = 0.f;
      if (gl < cn){
        nid = adj[o + c0 + gl];
        float s = ps[nid] + pdn;
        s = s > 0.f ? s : 0.2f * s;
        w = __expf(s - m) * inv;
      }
      for (int j = 0; j < cn; j++){
        float wj = __shfl(w, base + j);
        int   nj = __shfl(nid, base + j);
        #pragma unroll
        for (int r = 0; r < R; r++)
          acc[r] += wj * xin[(size_t)nj * DIM + gl + r * G];
      }
    }
  } else {
    for (int c0 = 0; c0 < dg; c0 += G){
      int cn = min(G, dg - c0);
      int nid = (gl < cn) ? adj[o + c0 + gl] : 0;
      for (int j = 0; j < cn; j++){
        int nj = __shfl(nid, base + j);
        #pragma unroll
        for (int r = 0; r < R; r++)
          acc[r] += xin[(size_t)nj * DIM + gl + r * G];
      }
    }
    float inv = dg > 0 ? 1.f / (float)dg : 0.f;
    #pragma unroll
    for (int r = 0; r < R; r++) acc[r] *= inv;
  }
  #pragma unroll
  for (int r = 0; r < R; r++){
    float v = acc[r];
    if (DO_SELU) v = selu_f(v);
    out[(size_t)node * DIM + gl + r * G] = v;
  }
}

// ---------- fused smoothing step: out[u] = pn[u]*scale * sum_{v in adj(u)} qn[v]*x[v] ----------
__global__ __launch_bounds__(256) void fused_smooth(
    const int* __restrict__ off, const int* __restrict__ degs, const int* __restrict__ adj,
    const float* __restrict__ pn, const float* __restrict__ qn,
    const float* __restrict__ scale,
    const float* __restrict__ xin, float* __restrict__ out, int N){
  const int G = 32;
  int t = blockIdx.x * 256 + threadIdx.x;
  int node = t / G, gl = t % G;
  if (node >= N) return;
  int base = (threadIdx.x & 63) & ~(G - 1);
  int o = off[node], dg = degs[node];
  float pnv = pn[node] * (scale ? scale[0] : 1.f);
  float acc = 0.f;
  for (int c0 = 0; c0 < dg; c0 += G){
    int cn = min(G, dg - c0);
    int nid = 0; float qv = 0.f;
    if (gl < cn){ nid = adj[o + c0 + gl]; qv = qn[nid]; }
    for (int j = 0; j < cn; j++){
      int   nj = __shfl(nid, base + j);
      float wj = __shfl(qv,  base + j);
      acc += wj * xin[(size_t)nj * 32 + gl];
    }
  }
  out[(size_t)node * 32 + gl] = pnv * acc;
}

// ---------- smoothing per-node coefficients ----------
__global__ void smooth_node(const int* __restrict__ deg, float* dis, float* pna, float* qn, int N){
  int n = blockIdx.x * blockDim.x + threadIdx.x;
  if (n >= N) return;
  float d = (float)deg[n];
  float di = d > 0.f ? powf(d, -0.6f) : 0.f;
  float d2 = d > 0.f ? powf(d, -0.5f) : 0.f;
  float al = 1.f / (1.f + logf(d + 1.f));
  dis[n] = di; pna[n] = d2 * al; qn[n] = d2;
}

// ---------- tiled f32 GEMM: C[M,K] = A[M,D] @ B  (optional selu epilogue) ----------
template<bool TRANSB, bool DO_SELU>
__global__ __launch_bounds__(256) void gemm_kernel(const float* __restrict__ A, const float* __restrict__ B,
                            float* __restrict__ C, int M, int D, int K){
  __shared__ float As[16][68];
  __shared__ float Bs[16][68];
  int tid = threadIdx.x;
  int tx = tid & 15, ty = tid >> 4;
  int row0 = blockIdx.x * 64;
  int col0 = blockIdx.y * 64;
  float acc[4][4] = {};
  for (int d0 = 0; d0 < D; d0 += 16){
    #pragma unroll
    for (int i = 0; i < 4; i++){
      int l = tid + i * 256;
      int m = l >> 4, d = l & 15;
      int r = row0 + m;
      As[d][m] = (r < M) ? A[(size_t)r * D + d0 + d] : 0.f;
    }
    #pragma unroll
    for (int i = 0; i < 4; i++){
      int l = tid + i * 256;
      int d, k;
      if (TRANSB){ d = l & 15; k = l >> 4; }
      else       { k = l & 63; d = l >> 6; }
      int kk = col0 + k;
      float v = 0.f;
      if (kk < K) v = TRANSB ? B[(size_t)kk * D + d0 + d] : B[(size_t)(d0 + d) * K + kk];
      Bs[d][k] = v;
    }
    __syncthreads();
    #pragma unroll
    for (int d = 0; d < 16; d++){
      float a[4], b[4];
      #pragma unroll
      for (int i = 0; i < 4; i++) a[i] = As[d][ty*4 + i];
      #pragma unroll
      for (int j = 0; j < 4; j++) b[j] = Bs[d][tx*4 + j];
      #pragma unroll
      for (int i = 0; i < 4; i++)
        #pragma unroll
        for (int j = 0; j < 4; j++)
          acc[i][j] += a[i] * b[j];
    }
    __syncthreads();
  }
  #pragma unroll
  for (int i = 0; i < 4; i++){
    int r = row0 + ty*4 + i;
    if (r >= M) continue;
    #pragma unroll
    for (int j = 0; j < 4; j++){
      int c = col0 + tx*4 + j;
      if (c >= K) continue;
      float v = acc[i][j];
      if (DO_SELU) v = selu_f(v);
      C[(size_t)r * K + c] = v;
    }
  }
}

extern "C" void kernel_launch(void* const* d_in, const int* in_sizes, int n_in,
                              void* d_out, int out_size, void* d_ws, size_t ws_size,
                              hipStream_t stream){
  const float* X    = (const float*)d_in[0];
  const int*   eidx = (const int*)d_in[1];
  const float* W1s  = (const float*)d_in[2];
  const float* W1d  = (const float*)d_in[3];
  const float* a1s  = (const float*)d_in[4];
  const float* a1d  = (const float*)d_in[5];
  const float* W2s  = (const float*)d_in[6];
  const float* W2d  = (const float*)d_in[7];
  const float* a2s  = (const float*)d_in[8];
  const float* a2d  = (const float*)d_in[9];
  const float* a3s  = (const float*)d_in[10];
  const float* a3d  = (const float*)d_in[11];
  const float* alpha1 = (const float*)d_in[14];
  const float* alpha2 = (const float*)d_in[15];

  const int N = in_sizes[0] / 256;
  const int E = in_sizes[1] / 2;
  const int* src = eidx;
  const int* dst = eidx + E;

  float* out_sm = (float*)d_out;                    // [N,32]
  float* out_h4 = (float*)d_out + (size_t)N * 32;   // [N,256]

  float* ws = (float*)d_ws;
  size_t o = 0;
  float* B1 = ws + o; o += (size_t)N * 128;  // xs1, later h3
  float* B2 = ws + o; o += (size_t)N * 128;  // h1, later agg(h3)
  float* B3 = ws + o; o += (size_t)N * 32;   // xs2, smooth tmp
  float* B4 = ws + o; o += (size_t)N * 32;   // h2 (smoothing seed)
  float* B5 = ws + o; o += (size_t)N * 32;   // agg3, smooth tmp
  float* ps = ws + o; o += N;
  float* pd = ws + o; o += N;
  int* deg_in  = (int*)(ws + o); o += N;
  int* deg_src = (int*)(ws + o); o += N;
  int* off_dst = (int*)(ws + o); o += N;
  int* off_src = (int*)(ws + o); o += N;
  int* cursor  = (int*)(ws + o); o += N;
  int* adj_dst = (int*)(ws + o); o += E;
  int* adj_src = (int*)(ws + o); o += E;
  int* bsums   = (int*)(ws + o); o += 256;
  int* bscan   = (int*)(ws + o); o += 256;
  float* dis = ws + o; o += N;
  float* pna = ws + o; o += N;
  float* qn  = ws + o; o += N;
  float* u1 = ws + o; o += 256;
  float* v1 = ws + o; o += 256;
  float* u2 = ws + o; o += 128;
  float* v2 = ws + o; o += 128;
  float* u3 = ws + o; o += 32;
  float* v3 = ws + o; o += 32;
  float* sscale = ws + o; o += 1;

  const int TPB = 256;
  const int EB = (E + TPB - 1) / TPB;
  const int NB_SCAN = (N + 1023) / 1024;
  auto blocksFor = [](size_t n){ return (unsigned)((n + 255) / 256); };

  // ---- graph preprocessing: degrees + two CSRs ----
  hipMemsetAsync(deg_in, 0, (size_t)N * 4, stream);
  hipMemsetAsync(deg_src, 0, (size_t)N * 4, stream);
  precompute_vecs<<<1, 256, 0, stream>>>(W1s, W1d, a1s, a1d, W2s, W2d, a2s, a2d,
                                         a3s, a3d, u1, v1, u2, v2, u3, v3,
                                         alpha1, alpha2, sscale);
  deg_int<<<EB, TPB, 0, stream>>>(src, dst, deg_src, deg_in, E);

  scan_block<<<NB_SCAN, 256, 0, stream>>>(deg_in, off_dst, bsums, N);
  scan_block<<<1, 256, 0, stream>>>(bsums, bscan, nullptr, NB_SCAN);
  scan_add<<<NB_SCAN, 256, 0, stream>>>(off_dst, bscan, N);
  scan_block<<<NB_SCAN, 256, 0, stream>>>(deg_src, off_src, bsums, N);
  scan_block<<<1, 256, 0, stream>>>(bsums, bscan, nullptr, NB_SCAN);
  scan_add<<<NB_SCAN, 256, 0, stream>>>(off_src, bscan, N);

  hipMemcpyAsync(cursor, off_dst, (size_t)N * 4, hipMemcpyDeviceToDevice, stream);
  scatter_csr<<<EB, TPB, 0, stream>>>(dst, src, cursor, adj_dst, E);
  hipMemcpyAsync(cursor, off_src, (size_t)N * 4, hipMemcpyDeviceToDevice, stream);
  scatter_csr<<<EB, TPB, 0, stream>>>(src, dst, cursor, adj_src, E);

  // ---- GAT layer 1: X(256) -> h1(128) ----
  node_dots<256><<<blocksFor((size_t)N * 64), TPB, 0, stream>>>(X, u1, v1, ps, pd, N);
  {
    dim3 g((N + 63) / 64, 2);
    gemm_kernel<false, false><<<g, TPB, 0, stream>>>(X, W1s, B1, N, 256, 128); // xs1
  }
  fused_gat<128, 64, true, true><<<blocksFor((size_t)N * 64), TPB, 0, stream>>>(
      off_dst, deg_in, adj_dst, ps, pd, B1, B2, N); // h1

  // ---- GAT layer 2: h1(128) -> h2(32) ----
  node_dots<128><<<blocksFor((size_t)N * 64), TPB, 0, stream>>>(B2, u2, v2, ps, pd, N);
  {
    dim3 g((N + 63) / 64, 1);
    gemm_kernel<false, false><<<g, TPB, 0, stream>>>(B2, W2s, B3, N, 128, 32); // xs2
  }
  fused_gat<32, 32, true, false><<<blocksFor((size_t)N * 32), TPB, 0, stream>>>(
      off_dst, deg_in, adj_dst, ps, pd, B3, B4, N); // h2

  // ---- GAT layer 3: h2(32) -> h3(128) ----
  node_dots<32><<<blocksFor((size_t)N * 64), TPB, 0, stream>>>(B4, u3, v3, ps, pd, N);
  fused_gat<32, 32, true, false><<<blocksFor((size_t)N * 32), TPB, 0, stream>>>(
      off_dst, deg_in, adj_dst, ps, pd, B4, B5, N); // agg3
  {
    dim3 g((N + 63) / 64, 2);
    gemm_kernel<true, true><<<g, TPB, 0, stream>>>(B5, W2s, B1, N, 32, 128); // h3
  }

  // ---- GAT layer 4 (uniform attention): aggregate h3 then GEMM with W1s^T ----
  fused_gat<128, 64, false, false><<<blocksFor((size_t)N * 64), TPB, 0, stream>>>(
      off_dst, deg_in, adj_dst, nullptr, nullptr, B1, B2, N);
  {
    dim3 g((N + 63) / 64, 4);
    gemm_kernel<true, false><<<g, TPB, 0, stream>>>(B2, W1s, out_h4, N, 128, 256); // h4
  }

  // ---- smoothing: sm = Norm^2 * (0.5(a1^2+4a2^2) * C^2 h2) ----
  smooth_node<<<(N + TPB - 1) / TPB, TPB, 0, stream>>>(deg_src, dis, pna, qn, N);
  fused_smooth<<<blocksFor((size_t)N * 32), TPB, 0, stream>>>(
      off_src, deg_src, adj_src, dis, dis, nullptr, B4, B3, N);
  fused_smooth<<<blocksFor((size_t)N * 32), TPB, 0, stream>>>(
      off_src, deg_src, adj_src, dis, dis, sscale, B3, B5, N);
  fused_smooth<<<blocksFor((size_t)N * 32), TPB, 0, stream>>>(
      off_src, deg_src, adj_src, pna, qn, nullptr, B5, B3, N);
  fused_smooth<<<blocksFor((size_t)N * 32), TPB, 0, stream>>>(
      off_src, deg_src, adj_src, pna, qn, nullptr, B3, out_sm, N);
}

// Round 3
// 823.559 us; speedup vs baseline: 2.5270x; 1.1825x over previous
//
#include <hip/hip_runtime.h>

// FlatST: GAT autoencoder + smoothing. CSR gather-aggregation (no atomics),
// bf16 MFMA GEMMs, bf16 gather operands for the 128-dim aggregations.
// N=100000, E=800000, IN=256, HID=128, OUT=32.

#define SELU_S 1.0507009873554805f
#define SELU_A 1.6732632423543772f

typedef short bf16x8 __attribute__((ext_vector_type(8)));
typedef float f32x4 __attribute__((ext_vector_type(4)));

__device__ __forceinline__ float selu_f(float v){
  return v > 0.f ? SELU_S * v : SELU_S * SELU_A * (__expf(v) - 1.f);
}
__device__ __forceinline__ float b2f(unsigned short u){
  return __uint_as_float((unsigned)u << 16);
}
__device__ __forceinline__ unsigned short f2b(float f){
  unsigned u = __float_as_uint(f);
  u += 0x7fffu + ((u >> 16) & 1u);   // RNE
  return (unsigned short)(u >> 16);
}

// ---------- conversions ----------
__global__ void cvt_bf16(const float* __restrict__ in, unsigned short* __restrict__ out, int n){
  int i = (blockIdx.x * blockDim.x + threadIdx.x) * 4;
  if (i + 3 < n){
    float4 v = *reinterpret_cast<const float4*>(in + i);
    uint2 r;
    r.x = (unsigned)f2b(v.x) | ((unsigned)f2b(v.y) << 16);
    r.y = (unsigned)f2b(v.z) | ((unsigned)f2b(v.w) << 16);
    *reinterpret_cast<uint2*>(out + i) = r;
  } else {
    for (; i < n; i++) out[i] = f2b(in[i]);
  }
}
// in [Ri][Ci] f32 -> out [Ci][Ri] bf16 (out[c*Ri + r] = in[r*Ci + c])
__global__ void tcvt_bf16(const float* __restrict__ in, unsigned short* __restrict__ out,
                          int Ri, int Ci){
  int o = blockIdx.x * blockDim.x + threadIdx.x;
  if (o >= Ri * Ci) return;
  int r = o % Ri, c = o / Ri;
  out[o] = f2b(in[r * Ci + c]);
}

// ---------- small precompute: u = W@a vectors + smoothing scalar ----------
__global__ void precompute_vecs(const float* __restrict__ W1s, const float* __restrict__ W1d,
                                const float* __restrict__ a1s, const float* __restrict__ a1d,
                                const float* __restrict__ W2s, const float* __restrict__ W2d,
                                const float* __restrict__ a2s, const float* __restrict__ a2d,
                                const float* __restrict__ a3s, const float* __restrict__ a3d,
                                float* u1, float* v1, float* u2, float* v2,
                                float* u3, float* v3,
                                const float* alpha1, const float* alpha2, float* sscale){
  int t = threadIdx.x; // 256 threads
  float s1 = 0.f, s2 = 0.f;
  for (int j = 0; j < 128; j++){ s1 += W1s[t*128+j]*a1s[j]; s2 += W1d[t*128+j]*a1d[j]; }
  u1[t] = s1; v1[t] = s2;
  if (t < 128){
    float s3 = 0.f, s4 = 0.f;
    for (int j = 0; j < 32; j++){ s3 += W2s[t*32+j]*a2s[j]; s4 += W2d[t*32+j]*a2d[j]; }
    u2[t] = s3; v2[t] = s4;
  }
  if (t < 32){
    float s5 = 0.f, s6 = 0.f;
    for (int j = 0; j < 128; j++){ s5 += W2s[j*32+t]*a3s[j]; s6 += W2d[j*32+t]*a3d[j]; }
    u3[t] = s5; v3[t] = s6;
  }
  if (t == 0){
    float a = alpha1[0], b = alpha2[0];
    sscale[0] = 0.5f * (a*a + 4.f*b*b);
  }
}

// ---------- per-node dot pair: p[n]=X[n]@u, q[n]=X[n]@v (one wave/node) ----------
template<int DIM, bool IN_BF16>
__global__ void node_dots(const void* __restrict__ X_, const float* __restrict__ u,
                          const float* __restrict__ v, float* __restrict__ p,
                          float* __restrict__ q, int N){
  int g = blockIdx.x * blockDim.x + threadIdx.x;
  int wave = g >> 6, lane = g & 63;
  if (wave >= N) return;
  float s1 = 0.f, s2 = 0.f;
  for (int k = lane; k < DIM; k += 64){
    float x;
    if (IN_BF16) x = b2f(((const unsigned short*)X_)[(size_t)wave*DIM + k]);
    else         x = ((const float*)X_)[(size_t)wave*DIM + k];
    s1 += x * u[k]; s2 += x * v[k];
  }
  for (int off = 32; off; off >>= 1){ s1 += __shfl_down(s1, off); s2 += __shfl_down(s2, off); }
  if (lane == 0){ p[wave] = s1; q[wave] = s2; }
}

// ---------- degree histograms (int) ----------
__global__ void deg_int(const int* __restrict__ src, const int* __restrict__ dst,
                        int* dsrc, int* ddst, int E){
  int e = blockIdx.x * blockDim.x + threadIdx.x;
  if (e >= E) return;
  atomicAdd(&dsrc[src[e]], 1);
  atomicAdd(&ddst[dst[e]], 1);
}

// ---------- hierarchical exclusive scan (1024 elems / block) ----------
__global__ void scan_block(const int* __restrict__ in, int* __restrict__ out,
                           int* __restrict__ bsums, int n){
  __shared__ int tmp[256];
  int tid = threadIdx.x;
  int base = blockIdx.x * 1024 + tid * 4;
  int v[4];
  #pragma unroll
  for (int i = 0; i < 4; i++) v[i] = (base + i < n) ? in[base + i] : 0;
  int ts = v[0] + v[1] + v[2] + v[3];
  tmp[tid] = ts; __syncthreads();
  for (int off = 1; off < 256; off <<= 1){
    int t = (tid >= off) ? tmp[tid - off] : 0;
    __syncthreads();
    tmp[tid] += t;
    __syncthreads();
  }
  int excl = tmp[tid] - ts;
  if (tid == 255 && bsums) bsums[blockIdx.x] = tmp[255];
  int run = excl;
  #pragma unroll
  for (int i = 0; i < 4; i++){ if (base + i < n) out[base + i] = run; run += v[i]; }
}
__global__ void scan_add(int* __restrict__ out, const int* __restrict__ bscan, int n){
  int base = blockIdx.x * 1024 + threadIdx.x * 4;
  int b = bscan[blockIdx.x];
  #pragma unroll
  for (int i = 0; i < 4; i++){ if (base + i < n) out[base + i] += b; }
}

// ---------- CSR scatter: adj[pos] = other endpoint ----------
__global__ void scatter_csr(const int* __restrict__ key, const int* __restrict__ other,
                            int* __restrict__ cursor, int* __restrict__ adj, int E){
  int e = blockIdx.x * blockDim.x + threadIdx.x;
  if (e >= E) return;
  int pos = atomicAdd(&cursor[key[e]], 1);
  adj[pos] = other[e];
}

// ---------- fused GAT layer: softmax attention + aggregate + norm + selu ----------
// One G-lane group per node. Feature element index = gl*R + r (lane-contiguous).
template<int DIM, int G, bool ATTN, bool DO_SELU, bool IN_BF16, bool OUT_BF16>
__global__ __launch_bounds__(256) void fused_gat(
    const int* __restrict__ off, const int* __restrict__ degs, const int* __restrict__ adj,
    const float* __restrict__ ps, const float* __restrict__ pd,
    const void* __restrict__ xin_, void* __restrict__ out_, int N){
  constexpr int R = DIM / G;
  int t = blockIdx.x * 256 + threadIdx.x;
  int node = t / G;
  int gl = t % G;
  if (node >= N) return;
  int base = (threadIdx.x & 63) & ~(G - 1);
  int o = off[node], dg = degs[node];
  float acc[R] = {};

  auto addNeighbor = [&](int nj, float wj){
    if (IN_BF16){
      const unsigned short* x = (const unsigned short*)xin_;
      if (R == 2){
        uint u = *reinterpret_cast<const uint*>(x + (size_t)nj * DIM + gl * 2);
        acc[0] += wj * __uint_as_float(u << 16);
        acc[1] += wj * __uint_as_float(u & 0xffff0000u);
      } else {
        #pragma unroll
        for (int r = 0; r < R; r++) acc[r] += wj * b2f(x[(size_t)nj * DIM + gl * R + r]);
      }
    } else {
      const float* x = (const float*)xin_;
      #pragma unroll
      for (int r = 0; r < R; r++) acc[r] += wj * x[(size_t)nj * DIM + gl * R + r];
    }
  };

  if (ATTN){
    float pdn = pd[node];
    float m = -1e30f;
    for (int k = gl; k < dg; k += G){
      float s = ps[adj[o + k]] + pdn;
      s = s > 0.f ? s : 0.2f * s;
      m = fmaxf(m, s);
    }
    for (int msk = G >> 1; msk; msk >>= 1) m = fmaxf(m, __shfl_xor(m, msk));
    float den = 0.f;
    for (int k = gl; k < dg; k += G){
      float s = ps[adj[o + k]] + pdn;
      s = s > 0.f ? s : 0.2f * s;
      den += __expf(s - m);
    }
    for (int msk = G >> 1; msk; msk >>= 1) den += __shfl_xor(den, msk);
    float inv = (dg > 0) ? 1.f / den : 0.f;
    for (int c0 = 0; c0 < dg; c0 += G){
      int cn = min(G, dg - c0);
      int nid = 0; float w = 0.f;
      if (gl < cn){
        nid = adj[o + c0 + gl];
        float s = ps[nid] + pdn;
        s = s > 0.f ? s : 0.2f * s;
        w = __expf(s - m) * inv;
      }
      for (int j = 0; j < cn; j++){
        float wj = __shfl(w, base + j);
        int   nj = __shfl(nid, base + j);
        addNeighbor(nj, wj);
      }
    }
  } else {
    for (int c0 = 0; c0 < dg; c0 += G){
      int cn = min(G, dg - c0);
      int nid = (gl < cn) ? adj[o + c0 + gl] : 0;
      for (int j = 0; j < cn; j++){
        int nj = __shfl(nid, base + j);
        addNeighbor(nj, 1.f);
      }
    }
    float inv = dg > 0 ? 1.f / (float)dg : 0.f;
    #pragma unroll
    for (int r = 0; r < R; r++) acc[r] *= inv;
  }
  #pragma unroll
  for (int r = 0; r < R; r++){
    if (DO_SELU) acc[r] = selu_f(acc[r]);
  }
  if (OUT_BF16){
    unsigned short* out = (unsigned short*)out_;
    if (R == 2){
      uint u = (uint)f2b(acc[0]) | ((uint)f2b(acc[1]) << 16);
      *reinterpret_cast<uint*>(out + (size_t)node * DIM + gl * 2) = u;
    } else {
      #pragma unroll
      for (int r = 0; r < R; r++) out[(size_t)node * DIM + gl * R + r] = f2b(acc[r]);
    }
  } else {
    float* out = (float*)out_;
    #pragma unroll
    for (int r = 0; r < R; r++) out[(size_t)node * DIM + gl * R + r] = acc[r];
  }
}

// ---------- fused smoothing step: out[u] = pn[u]*scale * sum_{v in adj(u)} qn[v]*x[v] ----------
__global__ __launch_bounds__(256) void fused_smooth(
    const int* __restrict__ off, const int* __restrict__ degs, const int* __restrict__ adj,
    const float* __restrict__ pn, const float* __restrict__ qn,
    const float* __restrict__ scale,
    const float* __restrict__ xin, float* __restrict__ out, int N){
  const int G = 32;
  int t = blockIdx.x * 256 + threadIdx.x;
  int node = t / G, gl = t % G;
  if (node >= N) return;
  int base = (threadIdx.x & 63) & ~(G - 1);
  int o = off[node], dg = degs[node];
  float pnv = pn[node] * (scale ? scale[0] : 1.f);
  float acc = 0.f;
  for (int c0 = 0; c0 < dg; c0 += G){
    int cn = min(G, dg - c0);
    int nid = 0; float qv = 0.f;
    if (gl < cn){ nid = adj[o + c0 + gl]; qv = qn[nid]; }
    for (int j = 0; j < cn; j++){
      int   nj = __shfl(nid, base + j);
      float wj = __shfl(qv,  base + j);
      acc += wj * xin[(size_t)nj * 32 + gl];
    }
  }
  out[(size_t)node * 32 + gl] = pnv * acc;
}

// ---------- smoothing per-node coefficients ----------
__global__ void smooth_node(const int* __restrict__ deg, float* dis, float* pna, float* qn, int N){
  int n = blockIdx.x * blockDim.x + threadIdx.x;
  if (n >= N) return;
  float d = (float)deg[n];
  float di = d > 0.f ? powf(d, -0.6f) : 0.f;
  float d2 = d > 0.f ? powf(d, -0.5f) : 0.f;
  float al = 1.f / (1.f + logf(d + 1.f));
  dis[n] = di; pna[n] = d2 * al; qn[n] = d2;
}

// ---------- bf16 MFMA GEMM: C[M,K] = A[M,D] @ Bt^T  (Bt stored [K][D] bf16) ----------
// Block = 256 thr = 4 waves; wave w handles rows [blk*64 + w*16, +16), all K cols.
// Fragment layouts (v_mfma_f32_16x16x32_bf16): A: row=lane&15, k=(lane>>4)*8+j;
// B: col=lane&15, k=(lane>>4)*8+j; C/D: col=lane&15, row=(lane>>4)*4+reg.
template<int D, int K, bool DO_SELU, bool OUT_BF16>
__global__ __launch_bounds__(256) void gemm_mfma(
    const unsigned short* __restrict__ A, const unsigned short* __restrict__ Bt,
    void* __restrict__ Cout, int M){
  constexpr int NF = K / 16;
  int wave = threadIdx.x >> 6;
  int lane = threadIdx.x & 63;
  int row0 = blockIdx.x * 64 + wave * 16;
  int arow = row0 + (lane & 15);
  int g8 = (lane >> 4) * 8;
  f32x4 acc[NF] = {};
  for (int k0 = 0; k0 < D; k0 += 32){
    bf16x8 a = {};
    if (arow < M) a = *reinterpret_cast<const bf16x8*>(A + (size_t)arow * D + k0 + g8);
    #pragma unroll
    for (int f = 0; f < NF; f++){
      bf16x8 b = *reinterpret_cast<const bf16x8*>(Bt + (size_t)(f * 16 + (lane & 15)) * D + k0 + g8);
      acc[f] = __builtin_amdgcn_mfma_f32_16x16x32_bf16(a, b, acc[f], 0, 0, 0);
    }
  }
  int crow = row0 + (lane >> 4) * 4;
  int ccol = lane & 15;
  #pragma unroll
  for (int f = 0; f < NF; f++){
    #pragma unroll
    for (int r = 0; r < 4; r++){
      int rr = crow + r;
      if (rr >= M) continue;
      float v = acc[f][r];
      if (DO_SELU) v = selu_f(v);
      if (OUT_BF16) ((unsigned short*)Cout)[(size_t)rr * K + f * 16 + ccol] = f2b(v);
      else          ((float*)Cout)[(size_t)rr * K + f * 16 + ccol] = v;
    }
  }
}

extern "C" void kernel_launch(void* const* d_in, const int* in_sizes, int n_in,
                              void* d_out, int out_size, void* d_ws, size_t ws_size,
                              hipStream_t stream){
  const float* X    = (const float*)d_in[0];
  const int*   eidx = (const int*)d_in[1];
  const float* W1s  = (const float*)d_in[2];
  const float* W1d  = (const float*)d_in[3];
  const float* a1s  = (const float*)d_in[4];
  const float* a1d  = (const float*)d_in[5];
  const float* W2s  = (const float*)d_in[6];
  const float* W2d  = (const float*)d_in[7];
  const float* a2s  = (const float*)d_in[8];
  const float* a2d  = (const float*)d_in[9];
  const float* a3s  = (const float*)d_in[10];
  const float* a3d  = (const float*)d_in[11];
  const float* alpha1 = (const float*)d_in[14];
  const float* alpha2 = (const float*)d_in[15];

  const int N = in_sizes[0] / 256;
  const int E = in_sizes[1] / 2;
  const int* src = eidx;
  const int* dst = eidx + E;

  float* out_sm = (float*)d_out;                    // [N,32]
  float* out_h4 = (float*)d_out + (size_t)N * 32;   // [N,256]

  float* ws = (float*)d_ws;
  size_t o = 0;
  // Region 0: Xh (N*256 bf16 = N*128 float slots); later aliased by S1/S2 (N*32 f32 each)
  unsigned short* Xh = (unsigned short*)(ws + o);
  float* S1 = ws + o;                 // alias (used after Xh is dead)
  float* S2 = ws + o + (size_t)N * 32;
  o += (size_t)N * 128;
  unsigned short* B1h   = (unsigned short*)(ws + o); o += (size_t)N * 64;  // xs1 / h3 (bf16 N*128)
  unsigned short* H1h   = (unsigned short*)(ws + o); o += (size_t)N * 64;  // h1 / agg4 (bf16 N*128)
  unsigned short* B3h   = (unsigned short*)(ws + o); o += (size_t)N * 16;  // xs2 (bf16 N*32)
  unsigned short* AGG3h = (unsigned short*)(ws + o); o += (size_t)N * 16;  // agg3 (bf16 N*32)
  float* B4 = ws + o; o += (size_t)N * 32;   // h2 (f32, smoothing seed)
  float* ps = ws + o; o += N;
  float* pd = ws + o; o += N;
  int* deg_in  = (int*)(ws + o); o += N;
  int* deg_src = (int*)(ws + o); o += N;
  int* off_dst = (int*)(ws + o); o += N;
  int* off_src = (int*)(ws + o); o += N;
  int* cursor  = (int*)(ws + o); o += N;
  int* adj_dst = (int*)(ws + o); o += E;
  int* adj_src = (int*)(ws + o); o += E;
  int* bsums   = (int*)(ws + o); o += 256;
  int* bscan   = (int*)(ws + o); o += 256;
  float* dis = ws + o; o += N;
  float* pna = ws + o; o += N;
  float* qn  = ws + o; o += N;
  unsigned short* W1sT_h = (unsigned short*)(ws + o); o += 128 * 256 / 2; // [128][256]
  unsigned short* W2sT_h = (unsigned short*)(ws + o); o += 32 * 128 / 2;  // [32][128]
  unsigned short* W2s_h  = (unsigned short*)(ws + o); o += 128 * 32 / 2;  // [128][32]
  unsigned short* W1s_h  = (unsigned short*)(ws + o); o += 256 * 128 / 2; // [256][128]
  float* u1 = ws + o; o += 256;
  float* v1 = ws + o; o += 256;
  float* u2 = ws + o; o += 128;
  float* v2 = ws + o; o += 128;
  float* u3 = ws + o; o += 32;
  float* v3 = ws + o; o += 32;
  float* sscale = ws + o; o += 1;

  const int TPB = 256;
  const int EB = (E + TPB - 1) / TPB;
  const int NB_SCAN = (N + 1023) / 1024;
  auto blocksFor = [](size_t n){ return (unsigned)((n + 255) / 256); };

  // ---- conversions + small precompute ----
  cvt_bf16<<<blocksFor(((size_t)N * 256 + 3) / 4), TPB, 0, stream>>>(X, Xh, N * 256);
  tcvt_bf16<<<blocksFor(256 * 128), TPB, 0, stream>>>(W1s, W1sT_h, 256, 128); // [128][256]
  tcvt_bf16<<<blocksFor(128 * 32), TPB, 0, stream>>>(W2s, W2sT_h, 128, 32);   // [32][128]
  cvt_bf16<<<blocksFor((128 * 32 + 3) / 4), TPB, 0, stream>>>(W2s, W2s_h, 128 * 32);
  cvt_bf16<<<blocksFor((256 * 128 + 3) / 4), TPB, 0, stream>>>(W1s, W1s_h, 256 * 128);
  precompute_vecs<<<1, 256, 0, stream>>>(W1s, W1d, a1s, a1d, W2s, W2d, a2s, a2d,
                                         a3s, a3d, u1, v1, u2, v2, u3, v3,
                                         alpha1, alpha2, sscale);

  // ---- graph preprocessing: degrees + two CSRs ----
  hipMemsetAsync(deg_in, 0, (size_t)N * 4, stream);
  hipMemsetAsync(deg_src, 0, (size_t)N * 4, stream);
  deg_int<<<EB, TPB, 0, stream>>>(src, dst, deg_src, deg_in, E);
  scan_block<<<NB_SCAN, 256, 0, stream>>>(deg_in, off_dst, bsums, N);
  scan_block<<<1, 256, 0, stream>>>(bsums, bscan, nullptr, NB_SCAN);
  scan_add<<<NB_SCAN, 256, 0, stream>>>(off_dst, bscan, N);
  scan_block<<<NB_SCAN, 256, 0, stream>>>(deg_src, off_src, bsums, N);
  scan_block<<<1, 256, 0, stream>>>(bsums, bscan, nullptr, NB_SCAN);
  scan_add<<<NB_SCAN, 256, 0, stream>>>(off_src, bscan, N);
  hipMemcpyAsync(cursor, off_dst, (size_t)N * 4, hipMemcpyDeviceToDevice, stream);
  scatter_csr<<<EB, TPB, 0, stream>>>(dst, src, cursor, adj_dst, E);
  hipMemcpyAsync(cursor, off_src, (size_t)N * 4, hipMemcpyDeviceToDevice, stream);
  scatter_csr<<<EB, TPB, 0, stream>>>(src, dst, cursor, adj_src, E);

  // ---- GAT layer 1: X(256) -> h1(128) ----
  node_dots<256, true><<<blocksFor((size_t)N * 64), TPB, 0, stream>>>(Xh, u1, v1, ps, pd, N);
  gemm_mfma<256, 128, false, true><<<(N + 63) / 64, TPB, 0, stream>>>(Xh, W1sT_h, B1h, N); // xs1
  fused_gat<128, 64, true, true, true, true><<<blocksFor((size_t)N * 64), TPB, 0, stream>>>(
      off_dst, deg_in, adj_dst, ps, pd, B1h, H1h, N); // h1 (bf16)

  // ---- GAT layer 2: h1(128) -> h2(32) ----
  node_dots<128, true><<<blocksFor((size_t)N * 64), TPB, 0, stream>>>(H1h, u2, v2, ps, pd, N);
  gemm_mfma<128, 32, false, true><<<(N + 63) / 64, TPB, 0, stream>>>(H1h, W2sT_h, B3h, N); // xs2
  fused_gat<32, 32, true, false, true, false><<<blocksFor((size_t)N * 32), TPB, 0, stream>>>(
      off_dst, deg_in, adj_dst, ps, pd, B3h, B4, N); // h2 (f32)

  // ---- GAT layer 3: h2(32) -> h3(128) ----
  node_dots<32, false><<<blocksFor((size_t)N * 64), TPB, 0, stream>>>(B4, u3, v3, ps, pd, N);
  fused_gat<32, 32, true, false, false, true><<<blocksFor((size_t)N * 32), TPB, 0, stream>>>(
      off_dst, deg_in, adj_dst, ps, pd, B4, AGG3h, N); // agg3 (bf16)
  gemm_mfma<32, 128, true, true><<<(N + 63) / 64, TPB, 0, stream>>>(AGG3h, W2s_h, B1h, N); // h3 (selu, bf16)

  // ---- GAT layer 4 (uniform): aggregate h3 then GEMM with W1s^T ----
  fused_gat<128, 64, false, false, true, true><<<blocksFor((size_t)N * 64), TPB, 0, stream>>>(
      off_dst, deg_in, adj_dst, nullptr, nullptr, B1h, H1h, N); // agg4 (bf16)
  gemm_mfma<128, 256, false, false><<<(N + 63) / 64, TPB, 0, stream>>>(H1h, W1s_h, out_h4, N); // h4 (f32)

  // ---- smoothing: sm = Norm^2 * (0.5(a1^2+4a2^2) * C^2 h2) ----
  smooth_node<<<(N + TPB - 1) / TPB, TPB, 0, stream>>>(deg_src, dis, pna, qn, N);
  fused_smooth<<<blocksFor((size_t)N * 32), TPB, 0, stream>>>(
      off_src, deg_src, adj_src, dis, dis, nullptr, B4, S1, N);
  fused_smooth<<<blocksFor((size_t)N * 32), TPB, 0, stream>>>(
      off_src, deg_src, adj_src, dis, dis, sscale, S1, S2, N);
  fused_smooth<<<blocksFor((size_t)N * 32), TPB, 0, stream>>>(
      off_src, deg_src, adj_src, pna, qn, nullptr, S2, S1, N);
  fused_smooth<<<blocksFor((size_t)N * 32), TPB, 0, stream>>>(
      off_src, deg_src, adj_src, pna, qn, nullptr, S1, out_sm, N);
}

// Round 4
// 759.094 us; speedup vs baseline: 2.7416x; 1.0849x over previous
//
#include <hip/hip_runtime.h>

// FlatST: GAT autoencoder + smoothing. CSR gather (no atomics), bf16 MFMA GEMMs,
// single-pass attention, producer-fused dots, bf16 smoothing tables.
// N=100000, E=800000, IN=256, HID=128, OUT=32.

#define SELU_S 1.0507009873554805f
#define SELU_A 1.6732632423543772f

typedef short bf16x8 __attribute__((ext_vector_type(8)));
typedef float f32x4 __attribute__((ext_vector_type(4)));

__device__ __forceinline__ float selu_f(float v){
  return v > 0.f ? SELU_S * v : SELU_S * SELU_A * (__expf(v) - 1.f);
}
__device__ __forceinline__ float b2f(unsigned short u){
  return __uint_as_float((unsigned)u << 16);
}
__device__ __forceinline__ unsigned short f2b(float f){
  unsigned u = __float_as_uint(f);
  u += 0x7fffu + ((u >> 16) & 1u);   // RNE
  return (unsigned short)(u >> 16);
}

// ---------- conversions ----------
__global__ void cvt_bf16(const float* __restrict__ in, unsigned short* __restrict__ out, int n){
  int i = (blockIdx.x * blockDim.x + threadIdx.x) * 4;
  if (i + 3 < n){
    float4 v = *reinterpret_cast<const float4*>(in + i);
    uint2 r;
    r.x = (unsigned)f2b(v.x) | ((unsigned)f2b(v.y) << 16);
    r.y = (unsigned)f2b(v.z) | ((unsigned)f2b(v.w) << 16);
    *reinterpret_cast<uint2*>(out + i) = r;
  } else {
    for (; i < n; i++) out[i] = f2b(in[i]);
  }
}
// in [Ri][Ci] f32 -> out [Ci][Ri] bf16
__global__ void tcvt_bf16(const float* __restrict__ in, unsigned short* __restrict__ out,
                          int Ri, int Ci){
  int o = blockIdx.x * blockDim.x + threadIdx.x;
  if (o >= Ri * Ci) return;
  int r = o % Ri, c = o / Ri;
  out[o] = f2b(in[r * Ci + c]);
}

// ---------- fused: X f32 -> Xh bf16 AND layer-1 dots p=X@u1, q=X@v1 ----------
__global__ __launch_bounds__(256) void cvt_dots(
    const float* __restrict__ X, unsigned short* __restrict__ Xh,
    const float* __restrict__ u1, const float* __restrict__ v1,
    float* __restrict__ p, float* __restrict__ q, int N){
  int g = blockIdx.x * 256 + threadIdx.x;
  int node = g >> 6, lane = g & 63;
  if (node >= N) return;
  float4 x = *reinterpret_cast<const float4*>(X + (size_t)node * 256 + lane * 4);
  uint2 r;
  r.x = (unsigned)f2b(x.x) | ((unsigned)f2b(x.y) << 16);
  r.y = (unsigned)f2b(x.z) | ((unsigned)f2b(x.w) << 16);
  *reinterpret_cast<uint2*>(Xh + (size_t)node * 256 + lane * 4) = r;
  float4 uu = *reinterpret_cast<const float4*>(u1 + lane * 4);
  float4 vv = *reinterpret_cast<const float4*>(v1 + lane * 4);
  float s1 = x.x*uu.x + x.y*uu.y + x.z*uu.z + x.w*uu.w;
  float s2 = x.x*vv.x + x.y*vv.y + x.z*vv.z + x.w*vv.w;
  for (int m = 32; m; m >>= 1){ s1 += __shfl_xor(s1, m); s2 += __shfl_xor(s2, m); }
  if (lane == 0){ p[node] = s1; q[node] = s2; }
}

// ---------- small precompute: u = W@a vectors + smoothing scalar ----------
__global__ void precompute_vecs(const float* __restrict__ W1s, const float* __restrict__ W1d,
                                const float* __restrict__ a1s, const float* __restrict__ a1d,
                                const float* __restrict__ W2s, const float* __restrict__ W2d,
                                const float* __restrict__ a2s, const float* __restrict__ a2d,
                                const float* __restrict__ a3s, const float* __restrict__ a3d,
                                float* u1, float* v1, float* u2, float* v2,
                                float* u3, float* v3,
                                const float* alpha1, const float* alpha2, float* sscale){
  int t = threadIdx.x; // 256 threads
  float s1 = 0.f, s2 = 0.f;
  for (int j = 0; j < 128; j++){ s1 += W1s[t*128+j]*a1s[j]; s2 += W1d[t*128+j]*a1d[j]; }
  u1[t] = s1; v1[t] = s2;
  if (t < 128){
    float s3 = 0.f, s4 = 0.f;
    for (int j = 0; j < 32; j++){ s3 += W2s[t*32+j]*a2s[j]; s4 += W2d[t*32+j]*a2d[j]; }
    u2[t] = s3; v2[t] = s4;
  }
  if (t < 32){
    float s5 = 0.f, s6 = 0.f;
    for (int j = 0; j < 128; j++){ s5 += W2s[j*32+t]*a3s[j]; s6 += W2d[j*32+t]*a3d[j]; }
    u3[t] = s5; v3[t] = s6;
  }
  if (t == 0){
    float a = alpha1[0], b = alpha2[0];
    sscale[0] = 0.5f * (a*a + 4.f*b*b);
  }
}

// ---------- degree histograms ----------
__global__ void deg_int(const int* __restrict__ src, const int* __restrict__ dst,
                        int* dsrc, int* ddst, int E){
  int e = blockIdx.x * blockDim.x + threadIdx.x;
  if (e >= E) return;
  atomicAdd(&dsrc[src[e]], 1);
  atomicAdd(&ddst[dst[e]], 1);
}

// ---------- hierarchical exclusive scan (1024 elems / block) ----------
__global__ void scan_block(const int* __restrict__ in, int* __restrict__ out,
                           int* __restrict__ bsums, int n){
  __shared__ int tmp[256];
  int tid = threadIdx.x;
  int base = blockIdx.x * 1024 + tid * 4;
  int v[4];
  #pragma unroll
  for (int i = 0; i < 4; i++) v[i] = (base + i < n) ? in[base + i] : 0;
  int ts = v[0] + v[1] + v[2] + v[3];
  tmp[tid] = ts; __syncthreads();
  for (int off = 1; off < 256; off <<= 1){
    int t = (tid >= off) ? tmp[tid - off] : 0;
    __syncthreads();
    tmp[tid] += t;
    __syncthreads();
  }
  int excl = tmp[tid] - ts;
  if (tid == 255 && bsums) bsums[blockIdx.x] = tmp[255];
  int run = excl;
  #pragma unroll
  for (int i = 0; i < 4; i++){ if (base + i < n) out[base + i] = run; run += v[i]; }
}
__global__ void scan_add(int* __restrict__ out, const int* __restrict__ bscan, int n){
  int base = blockIdx.x * 1024 + threadIdx.x * 4;
  int b = bscan[blockIdx.x];
  #pragma unroll
  for (int i = 0; i < 4; i++){ if (base + i < n) out[base + i] += b; }
}

// ---------- CSR scatter ----------
__global__ void scatter_csr(const int* __restrict__ key, const int* __restrict__ other,
                            int* __restrict__ cursor, int* __restrict__ adj, int E){
  int e = blockIdx.x * blockDim.x + threadIdx.x;
  if (e >= E) return;
  int pos = atomicAdd(&cursor[key[e]], 1);
  adj[pos] = other[e];
}

// ---------- fused GAT layer ----------
// One G-lane group per node; feature elem index = gl*R + r. Input always bf16.
// Fast path (dg<=G): single gather of scores, one exp per edge.
// DOTS: epilogue computes next-layer attention dots psn/pdn from the f32 acc.
template<int DIM, int G, bool ATTN, bool DO_SELU, bool OUT_BF16, bool DOTS>
__global__ __launch_bounds__(256) void fused_gat(
    const int* __restrict__ off, const int* __restrict__ degs, const int* __restrict__ adj,
    const float* __restrict__ ps, const float* __restrict__ pd,
    const unsigned short* __restrict__ xin, void* __restrict__ out_,
    const float* __restrict__ un, const float* __restrict__ vn,
    float* __restrict__ psn, float* __restrict__ pdn_o, int N){
  constexpr int R = DIM / G;
  int t = blockIdx.x * 256 + threadIdx.x;
  int node = t / G;
  int gl = t % G;
  if (node >= N) return;
  int base = (threadIdx.x & 63) & ~(G - 1);
  int o = off[node], dg = degs[node];
  float acc[R] = {};

  auto addNeighbor = [&](int nj, float wj){
    if (R == 2){
      uint u = *reinterpret_cast<const uint*>(xin + (size_t)nj * DIM + gl * 2);
      acc[0] += wj * __uint_as_float(u << 16);
      acc[1] += wj * __uint_as_float(u & 0xffff0000u);
    } else {
      #pragma unroll
      for (int r = 0; r < R; r++) acc[r] += wj * b2f(xin[(size_t)nj * DIM + gl * R + r]);
    }
  };

  if (ATTN){
    float pdn = pd[node];
    if (dg <= G){
      // single-pass: scores in registers
      int nid = -1;
      float s = -1e30f;
      if (gl < dg){
        nid = adj[o + gl];
        s = ps[nid] + pdn;
        s = s > 0.f ? s : 0.2f * s;
      }
      float m = s;
      for (int msk = G >> 1; msk; msk >>= 1) m = fmaxf(m, __shfl_xor(m, msk));
      float e = (gl < dg) ? __expf(s - m) : 0.f;
      float den = e;
      for (int msk = G >> 1; msk; msk >>= 1) den += __shfl_xor(den, msk);
      float w = (dg > 0) ? e / den : 0.f;
      for (int j = 0; j < dg; j++){
        float wj = __shfl(w, base + j);
        int   nj = __shfl(nid, base + j);
        addNeighbor(nj, wj);
      }
    } else {
      // generic 3-pass fallback (rare)
      float m = -1e30f;
      for (int k = gl; k < dg; k += G){
        float s = ps[adj[o + k]] + pdn;
        s = s > 0.f ? s : 0.2f * s;
        m = fmaxf(m, s);
      }
      for (int msk = G >> 1; msk; msk >>= 1) m = fmaxf(m, __shfl_xor(m, msk));
      float den = 0.f;
      for (int k = gl; k < dg; k += G){
        float s = ps[adj[o + k]] + pdn;
        s = s > 0.f ? s : 0.2f * s;
        den += __expf(s - m);
      }
      for (int msk = G >> 1; msk; msk >>= 1) den += __shfl_xor(den, msk);
      float inv = 1.f / den;
      for (int c0 = 0; c0 < dg; c0 += G){
        int cn = min(G, dg - c0);
        int nid = 0; float w = 0.f;
        if (gl < cn){
          nid = adj[o + c0 + gl];
          float s = ps[nid] + pdn;
          s = s > 0.f ? s : 0.2f * s;
          w = __expf(s - m) * inv;
        }
        for (int j = 0; j < cn; j++){
          float wj = __shfl(w, base + j);
          int   nj = __shfl(nid, base + j);
          addNeighbor(nj, wj);
        }
      }
    }
  } else {
    for (int c0 = 0; c0 < dg; c0 += G){
      int cn = min(G, dg - c0);
      int nid = (gl < cn) ? adj[o + c0 + gl] : 0;
      for (int j = 0; j < cn; j++){
        int nj = __shfl(nid, base + j);
        addNeighbor(nj, 1.f);
      }
    }
    float inv = dg > 0 ? 1.f / (float)dg : 0.f;
    #pragma unroll
    for (int r = 0; r < R; r++) acc[r] *= inv;
  }
  #pragma unroll
  for (int r = 0; r < R; r++){
    if (DO_SELU) acc[r] = selu_f(acc[r]);
  }
  if (DOTS){
    float s1 = 0.f, s2 = 0.f;
    #pragma unroll
    for (int r = 0; r < R; r++){
      s1 += acc[r] * un[gl * R + r];
      s2 += acc[r] * vn[gl * R + r];
    }
    for (int msk = G >> 1; msk; msk >>= 1){ s1 += __shfl_xor(s1, msk); s2 += __shfl_xor(s2, msk); }
    if (gl == 0){ psn[node] = s1; pdn_o[node] = s2; }
  }
  if (OUT_BF16){
    unsigned short* out = (unsigned short*)out_;
    if (R == 2){
      uint u = (uint)f2b(acc[0]) | ((uint)f2b(acc[1]) << 16);
      *reinterpret_cast<uint*>(out + (size_t)node * DIM + gl * 2) = u;
    } else {
      #pragma unroll
      for (int r = 0; r < R; r++) out[(size_t)node * DIM + gl * R + r] = f2b(acc[r]);
    }
  } else {
    float* out = (float*)out_;
    #pragma unroll
    for (int r = 0; r < R; r++) out[(size_t)node * DIM + gl * R + r] = acc[r];
  }
}

// ---------- fused smoothing step: out[u] = pn[u]*scale * sum_{v} qn[v]*x[v] ----------
// 32-dim, G=32; bf16 tables, f32 accumulate.
template<bool OUT_B>
__global__ __launch_bounds__(256) void fused_smooth(
    const int* __restrict__ off, const int* __restrict__ degs, const int* __restrict__ adj,
    const float* __restrict__ pn, const float* __restrict__ qn,
    const float* __restrict__ scale,
    const unsigned short* __restrict__ xin, void* __restrict__ out_, int N){
  const int G = 32;
  int t = blockIdx.x * 256 + threadIdx.x;
  int node = t / G, gl = t % G;
  if (node >= N) return;
  int base = (threadIdx.x & 63) & ~(G - 1);
  int o = off[node], dg = degs[node];
  float pnv = pn[node] * (scale ? scale[0] : 1.f);
  float acc = 0.f;
  for (int c0 = 0; c0 < dg; c0 += G){
    int cn = min(G, dg - c0);
    int nid = 0; float qv = 0.f;
    if (gl < cn){ nid = adj[o + c0 + gl]; qv = qn[nid]; }
    for (int j = 0; j < cn; j++){
      int   nj = __shfl(nid, base + j);
      float wj = __shfl(qv,  base + j);
      acc += wj * b2f(xin[(size_t)nj * 32 + gl]);
    }
  }
  float v = pnv * acc;
  if (OUT_B) ((unsigned short*)out_)[(size_t)node * 32 + gl] = f2b(v);
  else       ((float*)out_)[(size_t)node * 32 + gl] = v;
}

// ---------- smoothing per-node coefficients ----------
__global__ void smooth_node(const int* __restrict__ deg, float* dis, float* pna, float* qn, int N){
  int n = blockIdx.x * blockDim.x + threadIdx.x;
  if (n >= N) return;
  float d = (float)deg[n];
  float di = d > 0.f ? powf(d, -0.6f) : 0.f;
  float d2 = d > 0.f ? powf(d, -0.5f) : 0.f;
  float al = 1.f / (1.f + logf(d + 1.f));
  dis[n] = di; pna[n] = d2 * al; qn[n] = d2;
}

// ---------- bf16 MFMA GEMM: C[M,K] = A[M,D] @ Bt^T  (Bt stored [K][D] bf16) ----------
template<int D, int K, bool DO_SELU, bool OUT_BF16>
__global__ __launch_bounds__(256) void gemm_mfma(
    const unsigned short* __restrict__ A, const unsigned short* __restrict__ Bt,
    void* __restrict__ Cout, int M){
  constexpr int NF = K / 16;
  int wave = threadIdx.x >> 6;
  int lane = threadIdx.x & 63;
  int row0 = blockIdx.x * 64 + wave * 16;
  int arow = row0 + (lane & 15);
  int g8 = (lane >> 4) * 8;
  f32x4 acc[NF] = {};
  for (int k0 = 0; k0 < D; k0 += 32){
    bf16x8 a = {};
    if (arow < M) a = *reinterpret_cast<const bf16x8*>(A + (size_t)arow * D + k0 + g8);
    #pragma unroll
    for (int f = 0; f < NF; f++){
      bf16x8 b = *reinterpret_cast<const bf16x8*>(Bt + (size_t)(f * 16 + (lane & 15)) * D + k0 + g8);
      acc[f] = __builtin_amdgcn_mfma_f32_16x16x32_bf16(a, b, acc[f], 0, 0, 0);
    }
  }
  int crow = row0 + (lane >> 4) * 4;
  int ccol = lane & 15;
  #pragma unroll
  for (int f = 0; f < NF; f++){
    #pragma unroll
    for (int r = 0; r < 4; r++){
      int rr = crow + r;
      if (rr >= M) continue;
      float v = acc[f][r];
      if (DO_SELU) v = selu_f(v);
      if (OUT_BF16) ((unsigned short*)Cout)[(size_t)rr * K + f * 16 + ccol] = f2b(v);
      else          ((float*)Cout)[(size_t)rr * K + f * 16 + ccol] = v;
    }
  }
}

extern "C" void kernel_launch(void* const* d_in, const int* in_sizes, int n_in,
                              void* d_out, int out_size, void* d_ws, size_t ws_size,
                              hipStream_t stream){
  const float* X    = (const float*)d_in[0];
  const int*   eidx = (const int*)d_in[1];
  const float* W1s  = (const float*)d_in[2];
  const float* W1d  = (const float*)d_in[3];
  const float* a1s  = (const float*)d_in[4];
  const float* a1d  = (const float*)d_in[5];
  const float* W2s  = (const float*)d_in[6];
  const float* W2d  = (const float*)d_in[7];
  const float* a2s  = (const float*)d_in[8];
  const float* a2d  = (const float*)d_in[9];
  const float* a3s  = (const float*)d_in[10];
  const float* a3d  = (const float*)d_in[11];
  const float* alpha1 = (const float*)d_in[14];
  const float* alpha2 = (const float*)d_in[15];

  const int N = in_sizes[0] / 256;
  const int E = in_sizes[1] / 2;
  const int* src = eidx;
  const int* dst = eidx + E;

  float* out_sm = (float*)d_out;                    // [N,32]
  float* out_h4 = (float*)d_out + (size_t)N * 32;   // [N,256]

  float* ws = (float*)d_ws;
  size_t o = 0;
  unsigned short* Xh  = (unsigned short*)(ws + o); o += (size_t)N * 128; // [N,256] bf16
  unsigned short* B1h = (unsigned short*)(ws + o); o += (size_t)N * 64;  // xs1 / h3
  unsigned short* H1h = (unsigned short*)(ws + o); o += (size_t)N * 64;  // h1 / agg4
  unsigned short* B3h = (unsigned short*)(ws + o); o += (size_t)N * 16;  // xs2
  unsigned short* H2h = (unsigned short*)(ws + o); o += (size_t)N * 16;  // h2 (bf16)
  unsigned short* AGG3h = (unsigned short*)(ws + o); o += (size_t)N * 16; // agg3
  unsigned short* T1h = (unsigned short*)(ws + o); o += (size_t)N * 16;  // smooth tmp
  unsigned short* T2h = (unsigned short*)(ws + o); o += (size_t)N * 16;  // smooth tmp
  float* ps_a = ws + o; o += N;
  float* pd_a = ws + o; o += N;
  float* ps_b = ws + o; o += N;
  float* pd_b = ws + o; o += N;
  int* deg_in  = (int*)(ws + o); o += N;
  int* deg_src = (int*)(ws + o); o += N;
  int* off_dst = (int*)(ws + o); o += N;
  int* off_src = (int*)(ws + o); o += N;
  int* cursor  = (int*)(ws + o); o += N;
  int* adj_dst = (int*)(ws + o); o += E;
  int* adj_src = (int*)(ws + o); o += E;
  int* bsums   = (int*)(ws + o); o += 256;
  int* bscan   = (int*)(ws + o); o += 256;
  float* dis = ws + o; o += N;
  float* pna = ws + o; o += N;
  float* qn  = ws + o; o += N;
  unsigned short* W1sT_h = (unsigned short*)(ws + o); o += 128 * 256 / 2; // [128][256]
  unsigned short* W2sT_h = (unsigned short*)(ws + o); o += 32 * 128 / 2;  // [32][128]
  unsigned short* W2s_h  = (unsigned short*)(ws + o); o += 128 * 32 / 2;  // [128][32]
  unsigned short* W1s_h  = (unsigned short*)(ws + o); o += 256 * 128 / 2; // [256][128]
  float* u1 = ws + o; o += 256;
  float* v1 = ws + o; o += 256;
  float* u2 = ws + o; o += 128;
  float* v2 = ws + o; o += 128;
  float* u3 = ws + o; o += 32;
  float* v3 = ws + o; o += 32;
  float* sscale = ws + o; o += 1;

  const int TPB = 256;
  const int EB = (E + TPB - 1) / TPB;
  const int NB_SCAN = (N + 1023) / 1024;
  auto blocksFor = [](size_t n){ return (unsigned)((n + 255) / 256); };

  // ---- small precompute first (u1/v1 needed by cvt_dots) ----
  precompute_vecs<<<1, 256, 0, stream>>>(W1s, W1d, a1s, a1d, W2s, W2d, a2s, a2d,
                                         a3s, a3d, u1, v1, u2, v2, u3, v3,
                                         alpha1, alpha2, sscale);
  tcvt_bf16<<<blocksFor(256 * 128), TPB, 0, stream>>>(W1s, W1sT_h, 256, 128);
  tcvt_bf16<<<blocksFor(128 * 32), TPB, 0, stream>>>(W2s, W2sT_h, 128, 32);
  cvt_bf16<<<blocksFor((128 * 32 + 3) / 4), TPB, 0, stream>>>(W2s, W2s_h, 128 * 32);
  cvt_bf16<<<blocksFor((256 * 128 + 3) / 4), TPB, 0, stream>>>(W1s, W1s_h, 256 * 128);
  cvt_dots<<<blocksFor((size_t)N * 64), TPB, 0, stream>>>(X, Xh, u1, v1, ps_a, pd_a, N);

  // ---- graph preprocessing: degrees + two CSRs ----
  hipMemsetAsync(deg_in, 0, (size_t)N * 4, stream);
  hipMemsetAsync(deg_src, 0, (size_t)N * 4, stream);
  deg_int<<<EB, TPB, 0, stream>>>(src, dst, deg_src, deg_in, E);
  scan_block<<<NB_SCAN, 256, 0, stream>>>(deg_in, off_dst, bsums, N);
  scan_block<<<1, 256, 0, stream>>>(bsums, bscan, nullptr, NB_SCAN);
  scan_add<<<NB_SCAN, 256, 0, stream>>>(off_dst, bscan, N);
  scan_block<<<NB_SCAN, 256, 0, stream>>>(deg_src, off_src, bsums, N);
  scan_block<<<1, 256, 0, stream>>>(bsums, bscan, nullptr, NB_SCAN);
  scan_add<<<NB_SCAN, 256, 0, stream>>>(off_src, bscan, N);
  hipMemcpyAsync(cursor, off_dst, (size_t)N * 4, hipMemcpyDeviceToDevice, stream);
  scatter_csr<<<EB, TPB, 0, stream>>>(dst, src, cursor, adj_dst, E);
  hipMemcpyAsync(cursor, off_src, (size_t)N * 4, hipMemcpyDeviceToDevice, stream);
  scatter_csr<<<EB, TPB, 0, stream>>>(src, dst, cursor, adj_src, E);

  // ---- GAT layer 1: X(256) -> h1(128); epilogue dots for layer 2 ----
  gemm_mfma<256, 128, false, true><<<(N + 63) / 64, TPB, 0, stream>>>(Xh, W1sT_h, B1h, N); // xs1
  fused_gat<128, 64, true, true, true, true><<<blocksFor((size_t)N * 64), TPB, 0, stream>>>(
      off_dst, deg_in, adj_dst, ps_a, pd_a, B1h, H1h, u2, v2, ps_b, pd_b, N); // h1

  // ---- GAT layer 2: h1(128) -> h2(32); epilogue dots for layer 3 ----
  gemm_mfma<128, 32, false, true><<<(N + 63) / 64, TPB, 0, stream>>>(H1h, W2sT_h, B3h, N); // xs2
  fused_gat<32, 32, true, false, true, true><<<blocksFor((size_t)N * 32), TPB, 0, stream>>>(
      off_dst, deg_in, adj_dst, ps_b, pd_b, B3h, H2h, u3, v3, ps_a, pd_a, N); // h2 (bf16)

  // ---- GAT layer 3: h2(32) -> h3(128) ----
  fused_gat<32, 32, true, false, true, false><<<blocksFor((size_t)N * 32), TPB, 0, stream>>>(
      off_dst, deg_in, adj_dst, ps_a, pd_a, H2h, AGG3h, nullptr, nullptr, nullptr, nullptr, N);
  gemm_mfma<32, 128, true, true><<<(N + 63) / 64, TPB, 0, stream>>>(AGG3h, W2s_h, B1h, N); // h3

  // ---- GAT layer 4 (uniform): aggregate h3 then GEMM with W1s^T ----
  fused_gat<128, 64, false, false, true, false><<<blocksFor((size_t)N * 64), TPB, 0, stream>>>(
      off_dst, deg_in, adj_dst, nullptr, nullptr, B1h, H1h, nullptr, nullptr, nullptr, nullptr, N);
  gemm_mfma<128, 256, false, false><<<(N + 63) / 64, TPB, 0, stream>>>(H1h, W1s_h, out_h4, N); // h4

  // ---- smoothing: sm = Norm^2 * (0.5(a1^2+4a2^2) * C^2 h2), bf16 tables ----
  smooth_node<<<(N + TPB - 1) / TPB, TPB, 0, stream>>>(deg_src, dis, pna, qn, N);
  fused_smooth<true><<<blocksFor((size_t)N * 32), TPB, 0, stream>>>(
      off_src, deg_src, adj_src, dis, dis, nullptr, H2h, T1h, N);
  fused_smooth<true><<<blocksFor((size_t)N * 32), TPB, 0, stream>>>(
      off_src, deg_src, adj_src, dis, dis, sscale, T1h, T2h, N);
  fused_smooth<true><<<blocksFor((size_t)N * 32), TPB, 0, stream>>>(
      off_src, deg_src, adj_src, pna, qn, nullptr, T2h, T1h, N);
  fused_smooth<false><<<blocksFor((size_t)N * 32), TPB, 0, stream>>>(
      off_src, deg_src, adj_src, pna, qn, nullptr, T1h, out_sm, N);
}

// Round 5
// 623.672 us; speedup vs baseline: 3.3369x; 1.2171x over previous
//
#include <hip/hip_runtime.h>

// FlatST: GAT autoencoder + smoothing. CSR gather (no atomics), bf16 MFMA GEMMs,
// single-pass attention with 4x-unrolled neighbor gather (MLP), G=16 groups for
// 32-dim ops, bf16 tables everywhere.
// N=100000, E=800000, IN=256, HID=128, OUT=32.

#define SELU_S 1.0507009873554805f
#define SELU_A 1.6732632423543772f

typedef short bf16x8 __attribute__((ext_vector_type(8)));
typedef float f32x4 __attribute__((ext_vector_type(4)));

__device__ __forceinline__ float selu_f(float v){
  return v > 0.f ? SELU_S * v : SELU_S * SELU_A * (__expf(v) - 1.f);
}
__device__ __forceinline__ float b2f(unsigned short u){
  return __uint_as_float((unsigned)u << 16);
}
__device__ __forceinline__ unsigned short f2b(float f){
  unsigned u = __float_as_uint(f);
  u += 0x7fffu + ((u >> 16) & 1u);   // RNE
  return (unsigned short)(u >> 16);
}

// ---------- weight prep: bf16 copies + transposes of W1s, W2s ----------
__global__ __launch_bounds__(256) void prep_weights(
    const float* __restrict__ W1s, const float* __restrict__ W2s,
    unsigned short* __restrict__ W1sT_h, unsigned short* __restrict__ W1s_h,
    unsigned short* __restrict__ W2sT_h, unsigned short* __restrict__ W2s_h){
  int t = blockIdx.x * 256 + threadIdx.x;   // 32768 threads
  if (t < 32768){
    W1s_h[t] = f2b(W1s[t]);                  // [256][128]
    int k = t / 256, d = t % 256;            // W1sT_h [128][256]
    W1sT_h[t] = f2b(W1s[d * 128 + k]);
  }
  if (t < 4096){
    W2s_h[t] = f2b(W2s[t]);                  // [128][32]
    int k = t / 128, d = t % 128;            // W2sT_h [32][128]
    W2sT_h[t] = f2b(W2s[d * 32 + k]);
  }
}

// ---------- fused: X f32 -> Xh bf16 AND layer-1 dots p=X@u1, q=X@v1 ----------
__global__ __launch_bounds__(256) void cvt_dots(
    const float* __restrict__ X, unsigned short* __restrict__ Xh,
    const float* __restrict__ u1, const float* __restrict__ v1,
    float* __restrict__ p, float* __restrict__ q, int N){
  int g = blockIdx.x * 256 + threadIdx.x;
  int node = g >> 6, lane = g & 63;
  if (node >= N) return;
  float4 x = *reinterpret_cast<const float4*>(X + (size_t)node * 256 + lane * 4);
  uint2 r;
  r.x = (unsigned)f2b(x.x) | ((unsigned)f2b(x.y) << 16);
  r.y = (unsigned)f2b(x.z) | ((unsigned)f2b(x.w) << 16);
  *reinterpret_cast<uint2*>(Xh + (size_t)node * 256 + lane * 4) = r;
  float4 uu = *reinterpret_cast<const float4*>(u1 + lane * 4);
  float4 vv = *reinterpret_cast<const float4*>(v1 + lane * 4);
  float s1 = x.x*uu.x + x.y*uu.y + x.z*uu.z + x.w*uu.w;
  float s2 = x.x*vv.x + x.y*vv.y + x.z*vv.z + x.w*vv.w;
  for (int m = 32; m; m >>= 1){ s1 += __shfl_xor(s1, m); s2 += __shfl_xor(s2, m); }
  if (lane == 0){ p[node] = s1; q[node] = s2; }
}

// ---------- small precompute: u = W@a vectors + smoothing scalar ----------
__global__ void precompute_vecs(const float* __restrict__ W1s, const float* __restrict__ W1d,
                                const float* __restrict__ a1s, const float* __restrict__ a1d,
                                const float* __restrict__ W2s, const float* __restrict__ W2d,
                                const float* __restrict__ a2s, const float* __restrict__ a2d,
                                const float* __restrict__ a3s, const float* __restrict__ a3d,
                                float* u1, float* v1, float* u2, float* v2,
                                float* u3, float* v3,
                                const float* alpha1, const float* alpha2, float* sscale){
  int t = threadIdx.x; // 256 threads
  float s1 = 0.f, s2 = 0.f;
  for (int j = 0; j < 128; j++){ s1 += W1s[t*128+j]*a1s[j]; s2 += W1d[t*128+j]*a1d[j]; }
  u1[t] = s1; v1[t] = s2;
  if (t < 128){
    float s3 = 0.f, s4 = 0.f;
    for (int j = 0; j < 32; j++){ s3 += W2s[t*32+j]*a2s[j]; s4 += W2d[t*32+j]*a2d[j]; }
    u2[t] = s3; v2[t] = s4;
  }
  if (t < 32){
    float s5 = 0.f, s6 = 0.f;
    for (int j = 0; j < 128; j++){ s5 += W2s[j*32+t]*a3s[j]; s6 += W2d[j*32+t]*a3d[j]; }
    u3[t] = s5; v3[t] = s6;
  }
  if (t == 0){
    float a = alpha1[0], b = alpha2[0];
    sscale[0] = 0.5f * (a*a + 4.f*b*b);
  }
}

// ---------- degree histograms ----------
__global__ void deg_int(const int* __restrict__ src, const int* __restrict__ dst,
                        int* dsrc, int* ddst, int E){
  int e = blockIdx.x * blockDim.x + threadIdx.x;
  if (e >= E) return;
  atomicAdd(&dsrc[src[e]], 1);
  atomicAdd(&ddst[dst[e]], 1);
}

// ---------- hierarchical exclusive scan (1024 elems / block) ----------
__global__ void scan_block(const int* __restrict__ in, int* __restrict__ out,
                           int* __restrict__ bsums, int n){
  __shared__ int tmp[256];
  int tid = threadIdx.x;
  int base = blockIdx.x * 1024 + tid * 4;
  int v[4];
  #pragma unroll
  for (int i = 0; i < 4; i++) v[i] = (base + i < n) ? in[base + i] : 0;
  int ts = v[0] + v[1] + v[2] + v[3];
  tmp[tid] = ts; __syncthreads();
  for (int off = 1; off < 256; off <<= 1){
    int t = (tid >= off) ? tmp[tid - off] : 0;
    __syncthreads();
    tmp[tid] += t;
    __syncthreads();
  }
  int excl = tmp[tid] - ts;
  if (tid == 255 && bsums) bsums[blockIdx.x] = tmp[255];
  int run = excl;
  #pragma unroll
  for (int i = 0; i < 4; i++){ if (base + i < n) out[base + i] = run; run += v[i]; }
}
__global__ void scan_add(int* __restrict__ out, const int* __restrict__ bscan, int n){
  int base = blockIdx.x * 1024 + threadIdx.x * 4;
  int b = bscan[blockIdx.x];
  #pragma unroll
  for (int i = 0; i < 4; i++){ if (base + i < n) out[base + i] += b; }
}

// ---------- CSR scatter ----------
__global__ void scatter_csr(const int* __restrict__ key, const int* __restrict__ other,
                            int* __restrict__ cursor, int* __restrict__ adj, int E){
  int e = blockIdx.x * blockDim.x + threadIdx.x;
  if (e >= E) return;
  int pos = atomicAdd(&cursor[key[e]], 1);
  adj[pos] = other[e];
}

// ---------- fused GAT layer ----------
// One G-lane group per node; R = DIM/G = 2 (lane elems gl*2, gl*2+1).
// Fast path (dg<=G): scores in regs, one exp/edge; gather unrolled x4 for MLP.
template<int DIM, int G, bool ATTN, bool DO_SELU, bool OUT_BF16, bool DOTS>
__global__ __launch_bounds__(256) void fused_gat(
    const int* __restrict__ off, const int* __restrict__ degs, const int* __restrict__ adj,
    const float* __restrict__ ps, const float* __restrict__ pd,
    const unsigned short* __restrict__ xin, void* __restrict__ out_,
    const float* __restrict__ un, const float* __restrict__ vn,
    float* __restrict__ psn, float* __restrict__ pdn_o, int N){
  constexpr int R = DIM / G;
  static_assert(R == 2, "R must be 2");
  int t = blockIdx.x * 256 + threadIdx.x;
  int node = t / G;
  int gl = t % G;
  if (node >= N) return;
  int base = (threadIdx.x & 63) & ~(G - 1);
  int o = off[node], dg = degs[node];
  float acc0 = 0.f, acc1 = 0.f;

  auto ldu = [&](int nj) -> uint {
    return *reinterpret_cast<const uint*>(xin + (size_t)nj * DIM + gl * 2);
  };
  auto accum = [&](uint u, float wj){
    acc0 += wj * __uint_as_float(u << 16);
    acc1 += wj * __uint_as_float(u & 0xffff0000u);
  };

  if (ATTN){
    float pdn = pd[node];
    if (dg <= G){
      int nid = 0;
      float s = -1e30f;
      if (gl < dg){
        nid = adj[o + gl];
        s = ps[nid] + pdn;
        s = s > 0.f ? s : 0.2f * s;
      }
      float m = s;
      for (int msk = G >> 1; msk; msk >>= 1) m = fmaxf(m, __shfl_xor(m, msk));
      float e = (gl < dg) ? __expf(s - m) : 0.f;
      float den = e;
      for (int msk = G >> 1; msk; msk >>= 1) den += __shfl_xor(den, msk);
      float w = (dg > 0) ? e / den : 0.f;
      int j = 0;
      for (; j + 4 <= dg; j += 4){
        int   n0 = __shfl(nid, base+j),   n1 = __shfl(nid, base+j+1);
        int   n2 = __shfl(nid, base+j+2), n3 = __shfl(nid, base+j+3);
        float w0 = __shfl(w, base+j),     w1 = __shfl(w, base+j+1);
        float w2 = __shfl(w, base+j+2),   w3 = __shfl(w, base+j+3);
        uint u0 = ldu(n0), u1 = ldu(n1), u2 = ldu(n2), u3 = ldu(n3);
        accum(u0, w0); accum(u1, w1); accum(u2, w2); accum(u3, w3);
      }
      for (; j < dg; j++){
        int nj = __shfl(nid, base+j);
        float wj = __shfl(w, base+j);
        accum(ldu(nj), wj);
      }
    } else {
      // generic 3-pass fallback (rare)
      float m = -1e30f;
      for (int k = gl; k < dg; k += G){
        float s = ps[adj[o + k]] + pdn;
        s = s > 0.f ? s : 0.2f * s;
        m = fmaxf(m, s);
      }
      for (int msk = G >> 1; msk; msk >>= 1) m = fmaxf(m, __shfl_xor(m, msk));
      float den = 0.f;
      for (int k = gl; k < dg; k += G){
        float s = ps[adj[o + k]] + pdn;
        s = s > 0.f ? s : 0.2f * s;
        den += __expf(s - m);
      }
      for (int msk = G >> 1; msk; msk >>= 1) den += __shfl_xor(den, msk);
      float inv = 1.f / den;
      for (int c0 = 0; c0 < dg; c0 += G){
        int cn = min(G, dg - c0);
        int nid = 0; float w = 0.f;
        if (gl < cn){
          nid = adj[o + c0 + gl];
          float s = ps[nid] + pdn;
          s = s > 0.f ? s : 0.2f * s;
          w = __expf(s - m) * inv;
        }
        for (int j = 0; j < cn; j++){
          float wj = __shfl(w, base + j);
          int   nj = __shfl(nid, base + j);
          accum(ldu(nj), wj);
        }
      }
    }
  } else {
    for (int c0 = 0; c0 < dg; c0 += G){
      int cn = min(G, dg - c0);
      int nid = (gl < cn) ? adj[o + c0 + gl] : 0;
      int j = 0;
      for (; j + 4 <= cn; j += 4){
        int n0 = __shfl(nid, base+j),   n1 = __shfl(nid, base+j+1);
        int n2 = __shfl(nid, base+j+2), n3 = __shfl(nid, base+j+3);
        uint u0 = ldu(n0), u1 = ldu(n1), u2 = ldu(n2), u3 = ldu(n3);
        accum(u0, 1.f); accum(u1, 1.f); accum(u2, 1.f); accum(u3, 1.f);
      }
      for (; j < cn; j++){
        int nj = __shfl(nid, base + j);
        accum(ldu(nj), 1.f);
      }
    }
    float inv = dg > 0 ? 1.f / (float)dg : 0.f;
    acc0 *= inv; acc1 *= inv;
  }
  if (DO_SELU){ acc0 = selu_f(acc0); acc1 = selu_f(acc1); }
  if (DOTS){
    float s1 = acc0 * un[gl*2] + acc1 * un[gl*2+1];
    float s2 = acc0 * vn[gl*2] + acc1 * vn[gl*2+1];
    for (int msk = G >> 1; msk; msk >>= 1){ s1 += __shfl_xor(s1, msk); s2 += __shfl_xor(s2, msk); }
    if (gl == 0){ psn[node] = s1; pdn_o[node] = s2; }
  }
  if (OUT_BF16){
    unsigned short* out = (unsigned short*)out_;
    uint u = (uint)f2b(acc0) | ((uint)f2b(acc1) << 16);
    *reinterpret_cast<uint*>(out + (size_t)node * DIM + gl * 2) = u;
  } else {
    float* out = (float*)out_;
    out[(size_t)node * DIM + gl*2] = acc0;
    out[(size_t)node * DIM + gl*2 + 1] = acc1;
  }
}

// ---------- fused smoothing step: out[u] = pn[u]*scale * sum_{v} qn[v]*x[v] ----------
// 32-dim, G=16 (4 nodes/wave); bf16 tables, f32 accumulate; x4 unrolled gather.
template<bool OUT_B>
__global__ __launch_bounds__(256) void fused_smooth(
    const int* __restrict__ off, const int* __restrict__ degs, const int* __restrict__ adj,
    const float* __restrict__ pn, const float* __restrict__ qn,
    const float* __restrict__ scale,
    const unsigned short* __restrict__ xin, void* __restrict__ out_, int N){
  const int G = 16;
  int t = blockIdx.x * 256 + threadIdx.x;
  int node = t / G, gl = t % G;
  if (node >= N) return;
  int base = (threadIdx.x & 63) & ~(G - 1);
  int o = off[node], dg = degs[node];
  float pnv = pn[node] * (scale ? scale[0] : 1.f);
  float acc0 = 0.f, acc1 = 0.f;
  auto ldu = [&](int nj) -> uint {
    return *reinterpret_cast<const uint*>(xin + (size_t)nj * 32 + gl * 2);
  };
  for (int c0 = 0; c0 < dg; c0 += G){
    int cn = min(G, dg - c0);
    int nid = 0; float qv = 0.f;
    if (gl < cn){ nid = adj[o + c0 + gl]; qv = qn[nid]; }
    int j = 0;
    for (; j + 4 <= cn; j += 4){
      int   n0 = __shfl(nid, base+j),   n1 = __shfl(nid, base+j+1);
      int   n2 = __shfl(nid, base+j+2), n3 = __shfl(nid, base+j+3);
      float q0 = __shfl(qv, base+j),    q1 = __shfl(qv, base+j+1);
      float q2 = __shfl(qv, base+j+2),  q3 = __shfl(qv, base+j+3);
      uint u0 = ldu(n0), u1 = ldu(n1), u2 = ldu(n2), u3 = ldu(n3);
      acc0 += q0 * __uint_as_float(u0 << 16); acc1 += q0 * __uint_as_float(u0 & 0xffff0000u);
      acc0 += q1 * __uint_as_float(u1 << 16); acc1 += q1 * __uint_as_float(u1 & 0xffff0000u);
      acc0 += q2 * __uint_as_float(u2 << 16); acc1 += q2 * __uint_as_float(u2 & 0xffff0000u);
      acc0 += q3 * __uint_as_float(u3 << 16); acc1 += q3 * __uint_as_float(u3 & 0xffff0000u);
    }
    for (; j < cn; j++){
      int   nj = __shfl(nid, base + j);
      float wj = __shfl(qv,  base + j);
      uint u = ldu(nj);
      acc0 += wj * __uint_as_float(u << 16);
      acc1 += wj * __uint_as_float(u & 0xffff0000u);
    }
  }
  acc0 *= pnv; acc1 *= pnv;
  if (OUT_B){
    uint u = (uint)f2b(acc0) | ((uint)f2b(acc1) << 16);
    *reinterpret_cast<uint*>((unsigned short*)out_ + (size_t)node * 32 + gl * 2) = u;
  } else {
    float2 v; v.x = acc0; v.y = acc1;
    *reinterpret_cast<float2*>((float*)out_ + (size_t)node * 32 + gl * 2) = v;
  }
}

// ---------- smoothing per-node coefficients ----------
__global__ void smooth_node(const int* __restrict__ deg, float* dis, float* pna, float* qn, int N){
  int n = blockIdx.x * blockDim.x + threadIdx.x;
  if (n >= N) return;
  float d = (float)deg[n];
  float di = d > 0.f ? powf(d, -0.6f) : 0.f;
  float d2 = d > 0.f ? powf(d, -0.5f) : 0.f;
  float al = 1.f / (1.f + logf(d + 1.f));
  dis[n] = di; pna[n] = d2 * al; qn[n] = d2;
}

// ---------- bf16 MFMA GEMM: C[M,K] = A[M,D] @ Bt^T  (Bt stored [K][D] bf16) ----------
template<int D, int K, bool DO_SELU, bool OUT_BF16>
__global__ __launch_bounds__(256) void gemm_mfma(
    const unsigned short* __restrict__ A, const unsigned short* __restrict__ Bt,
    void* __restrict__ Cout, int M){
  constexpr int NF = K / 16;
  int wave = threadIdx.x >> 6;
  int lane = threadIdx.x & 63;
  int row0 = blockIdx.x * 64 + wave * 16;
  int arow = row0 + (lane & 15);
  int g8 = (lane >> 4) * 8;
  f32x4 acc[NF] = {};
  for (int k0 = 0; k0 < D; k0 += 32){
    bf16x8 a = {};
    if (arow < M) a = *reinterpret_cast<const bf16x8*>(A + (size_t)arow * D + k0 + g8);
    #pragma unroll
    for (int f = 0; f < NF; f++){
      bf16x8 b = *reinterpret_cast<const bf16x8*>(Bt + (size_t)(f * 16 + (lane & 15)) * D + k0 + g8);
      acc[f] = __builtin_amdgcn_mfma_f32_16x16x32_bf16(a, b, acc[f], 0, 0, 0);
    }
  }
  int crow = row0 + (lane >> 4) * 4;
  int ccol = lane & 15;
  #pragma unroll
  for (int f = 0; f < NF; f++){
    #pragma unroll
    for (int r = 0; r < 4; r++){
      int rr = crow + r;
      if (rr >= M) continue;
      float v = acc[f][r];
      if (DO_SELU) v = selu_f(v);
      if (OUT_BF16) ((unsigned short*)Cout)[(size_t)rr * K + f * 16 + ccol] = f2b(v);
      else          ((float*)Cout)[(size_t)rr * K + f * 16 + ccol] = v;
    }
  }
}

extern "C" void kernel_launch(void* const* d_in, const int* in_sizes, int n_in,
                              void* d_out, int out_size, void* d_ws, size_t ws_size,
                              hipStream_t stream){
  const float* X    = (const float*)d_in[0];
  const int*   eidx = (const int*)d_in[1];
  const float* W1s  = (const float*)d_in[2];
  const float* W1d  = (const float*)d_in[3];
  const float* a1s  = (const float*)d_in[4];
  const float* a1d  = (const float*)d_in[5];
  const float* W2s  = (const float*)d_in[6];
  const float* W2d  = (const float*)d_in[7];
  const float* a2s  = (const float*)d_in[8];
  const float* a2d  = (const float*)d_in[9];
  const float* a3s  = (const float*)d_in[10];
  const float* a3d  = (const float*)d_in[11];
  const float* alpha1 = (const float*)d_in[14];
  const float* alpha2 = (const float*)d_in[15];

  const int N = in_sizes[0] / 256;
  const int E = in_sizes[1] / 2;
  const int* src = eidx;
  const int* dst = eidx + E;

  float* out_sm = (float*)d_out;                    // [N,32]
  float* out_h4 = (float*)d_out + (size_t)N * 32;   // [N,256]

  float* ws = (float*)d_ws;
  size_t o = 0;
  unsigned short* Xh  = (unsigned short*)(ws + o); o += (size_t)N * 128; // [N,256] bf16
  unsigned short* B1h = (unsigned short*)(ws + o); o += (size_t)N * 64;  // xs1 / h3
  unsigned short* H1h = (unsigned short*)(ws + o); o += (size_t)N * 64;  // h1 / agg4
  unsigned short* B3h = (unsigned short*)(ws + o); o += (size_t)N * 16;  // xs2
  unsigned short* H2h = (unsigned short*)(ws + o); o += (size_t)N * 16;  // h2 (bf16)
  unsigned short* AGG3h = (unsigned short*)(ws + o); o += (size_t)N * 16; // agg3
  unsigned short* T1h = (unsigned short*)(ws + o); o += (size_t)N * 16;  // smooth tmp
  unsigned short* T2h = (unsigned short*)(ws + o); o += (size_t)N * 16;  // smooth tmp
  float* ps_a = ws + o; o += N;
  float* pd_a = ws + o; o += N;
  float* ps_b = ws + o; o += N;
  float* pd_b = ws + o; o += N;
  int* deg_in  = (int*)(ws + o); o += N;
  int* deg_src = (int*)(ws + o); o += N;
  int* off_dst = (int*)(ws + o); o += N;
  int* off_src = (int*)(ws + o); o += N;
  int* cursor  = (int*)(ws + o); o += N;
  int* adj_dst = (int*)(ws + o); o += E;
  int* adj_src = (int*)(ws + o); o += E;
  int* bsums   = (int*)(ws + o); o += 256;
  int* bscan   = (int*)(ws + o); o += 256;
  float* dis = ws + o; o += N;
  float* pna = ws + o; o += N;
  float* qn  = ws + o; o += N;
  unsigned short* W1sT_h = (unsigned short*)(ws + o); o += 128 * 256 / 2; // [128][256]
  unsigned short* W2sT_h = (unsigned short*)(ws + o); o += 32 * 128 / 2;  // [32][128]
  unsigned short* W2s_h  = (unsigned short*)(ws + o); o += 128 * 32 / 2;  // [128][32]
  unsigned short* W1s_h  = (unsigned short*)(ws + o); o += 256 * 128 / 2; // [256][128]
  float* u1 = ws + o; o += 256;
  float* v1 = ws + o; o += 256;
  float* u2 = ws + o; o += 128;
  float* v2 = ws + o; o += 128;
  float* u3 = ws + o; o += 32;
  float* v3 = ws + o; o += 32;
  float* sscale = ws + o; o += 1;

  const int TPB = 256;
  const int EB = (E + TPB - 1) / TPB;
  const int NB_SCAN = (N + 1023) / 1024;
  auto blocksFor = [](size_t n){ return (unsigned)((n + 255) / 256); };

  // ---- small precompute first (u1/v1 needed by cvt_dots) ----
  precompute_vecs<<<1, 256, 0, stream>>>(W1s, W1d, a1s, a1d, W2s, W2d, a2s, a2d,
                                         a3s, a3d, u1, v1, u2, v2, u3, v3,
                                         alpha1, alpha2, sscale);
  prep_weights<<<128, 256, 0, stream>>>(W1s, W2s, W1sT_h, W1s_h, W2sT_h, W2s_h);
  cvt_dots<<<blocksFor((size_t)N * 64), TPB, 0, stream>>>(X, Xh, u1, v1, ps_a, pd_a, N);

  // ---- graph preprocessing: degrees + two CSRs ----
  hipMemsetAsync(deg_in, 0, (size_t)N * 4, stream);
  hipMemsetAsync(deg_src, 0, (size_t)N * 4, stream);
  deg_int<<<EB, TPB, 0, stream>>>(src, dst, deg_src, deg_in, E);
  scan_block<<<NB_SCAN, 256, 0, stream>>>(deg_in, off_dst, bsums, N);
  scan_block<<<1, 256, 0, stream>>>(bsums, bscan, nullptr, NB_SCAN);
  scan_add<<<NB_SCAN, 256, 0, stream>>>(off_dst, bscan, N);
  scan_block<<<NB_SCAN, 256, 0, stream>>>(deg_src, off_src, bsums, N);
  scan_block<<<1, 256, 0, stream>>>(bsums, bscan, nullptr, NB_SCAN);
  scan_add<<<NB_SCAN, 256, 0, stream>>>(off_src, bscan, N);
  hipMemcpyAsync(cursor, off_dst, (size_t)N * 4, hipMemcpyDeviceToDevice, stream);
  scatter_csr<<<EB, TPB, 0, stream>>>(dst, src, cursor, adj_dst, E);
  hipMemcpyAsync(cursor, off_src, (size_t)N * 4, hipMemcpyDeviceToDevice, stream);
  scatter_csr<<<EB, TPB, 0, stream>>>(src, dst, cursor, adj_src, E);

  // ---- GAT layer 1: X(256) -> h1(128); epilogue dots for layer 2 ----
  gemm_mfma<256, 128, false, true><<<(N + 63) / 64, TPB, 0, stream>>>(Xh, W1sT_h, B1h, N); // xs1
  fused_gat<128, 64, true, true, true, true><<<blocksFor((size_t)N * 64), TPB, 0, stream>>>(
      off_dst, deg_in, adj_dst, ps_a, pd_a, B1h, H1h, u2, v2, ps_b, pd_b, N); // h1

  // ---- GAT layer 2: h1(128) -> h2(32); epilogue dots for layer 3 ----
  gemm_mfma<128, 32, false, true><<<(N + 63) / 64, TPB, 0, stream>>>(H1h, W2sT_h, B3h, N); // xs2
  fused_gat<32, 16, true, false, true, true><<<blocksFor((size_t)N * 16), TPB, 0, stream>>>(
      off_dst, deg_in, adj_dst, ps_b, pd_b, B3h, H2h, u3, v3, ps_a, pd_a, N); // h2 (bf16)

  // ---- GAT layer 3: h2(32) -> h3(128) ----
  fused_gat<32, 16, true, false, true, false><<<blocksFor((size_t)N * 16), TPB, 0, stream>>>(
      off_dst, deg_in, adj_dst, ps_a, pd_a, H2h, AGG3h, nullptr, nullptr, nullptr, nullptr, N);
  gemm_mfma<32, 128, true, true><<<(N + 63) / 64, TPB, 0, stream>>>(AGG3h, W2s_h, B1h, N); // h3

  // ---- GAT layer 4 (uniform): aggregate h3 then GEMM with W1s^T ----
  fused_gat<128, 64, false, false, true, false><<<blocksFor((size_t)N * 64), TPB, 0, stream>>>(
      off_dst, deg_in, adj_dst, nullptr, nullptr, B1h, H1h, nullptr, nullptr, nullptr, nullptr, N);
  gemm_mfma<128, 256, false, false><<<(N + 63) / 64, TPB, 0, stream>>>(H1h, W1s_h, out_h4, N); // h4

  // ---- smoothing: sm = Norm^2 * (0.5(a1^2+4a2^2) * C^2 h2), bf16 tables ----
  smooth_node<<<(N + TPB - 1) / TPB, TPB, 0, stream>>>(deg_src, dis, pna, qn, N);
  fused_smooth<true><<<blocksFor((size_t)N * 16), TPB, 0, stream>>>(
      off_src, deg_src, adj_src, dis, dis, nullptr, H2h, T1h, N);
  fused_smooth<true><<<blocksFor((size_t)N * 16), TPB, 0, stream>>>(
      off_src, deg_src, adj_src, dis, dis, sscale, T1h, T2h, N);
  fused_smooth<true><<<blocksFor((size_t)N * 16), TPB, 0, stream>>>(
      off_src, deg_src, adj_src, pna, qn, nullptr, T2h, T1h, N);
  fused_smooth<false><<<blocksFor((size_t)N * 16), TPB, 0, stream>>>(
      off_src, deg_src, adj_src, pna, qn, nullptr, T1h, out_sm, N);
}